// Round 6
// baseline (595.392 us; speedup 1.0000x reference)
//
#include <hip/hip_runtime.h>

#define T_TOK 4096
#define HD 2048
#define NE 8
#define NI 1408

typedef __bf16 bf16x8 __attribute__((ext_vector_type(8)));
typedef __bf16 bf16x4 __attribute__((ext_vector_type(4)));
typedef float f32x4 __attribute__((ext_vector_type(4)));
typedef unsigned short ushort8 __attribute__((ext_vector_type(8)));

#define S_WAITCNT_VMCNT(n) asm volatile("s_waitcnt vmcnt(" #n ")" ::: "memory")
#define S_WAITCNT_LGKM0() asm volatile("s_waitcnt lgkmcnt(0)" ::: "memory")
__device__ __forceinline__ void wave_barrier() {
  asm volatile("" ::: "memory");
  __builtin_amdgcn_s_barrier();
  asm volatile("" ::: "memory");
}

__device__ __forceinline__ unsigned short f2bf(float f) {
  unsigned int u = __float_as_uint(f);
  u += 0x7FFFu + ((u >> 16) & 1u);
  return (unsigned short)(u >> 16);
}
__device__ __forceinline__ float bf2f(unsigned short u) {
  return __uint_as_float((unsigned int)u << 16);
}

__device__ __forceinline__ void gload_lds16(const void* g, void* l) {
  __builtin_amdgcn_global_load_lds(
      (const __attribute__((address_space(1))) unsigned int*)g,
      (__attribute__((address_space(3))) unsigned int*)l, 16, 0, 0);
}

// ---------------- routing (also emits x in bf16) ----------------
__global__ void router_kernel(const float* __restrict__ x,
                              const float* __restrict__ Wr,
                              float* __restrict__ logits,
                              unsigned short* __restrict__ xbf,
                              int4* __restrict__ tokinfo,
                              int* __restrict__ cnt) {
  int wv = threadIdx.x >> 6, lane = threadIdx.x & 63;
  int t = blockIdx.x * 4 + wv;
  const float* xr = x + (size_t)t * HD;
  unsigned short* xbr = xbf + (size_t)t * HD;
  float acc[NE];
#pragma unroll
  for (int e = 0; e < NE; e++) acc[e] = 0.f;
  for (int hi = 0; hi < HD / 64; hi++) {
    int h = hi * 64 + lane;
    float xv = xr[h];
    xbr[h] = f2bf(xv);
    const float4* w4 = (const float4*)(Wr + (size_t)h * NE);
    float4 a = w4[0], b = w4[1];
    acc[0] += xv * a.x; acc[1] += xv * a.y; acc[2] += xv * a.z; acc[3] += xv * a.w;
    acc[4] += xv * b.x; acc[5] += xv * b.y; acc[6] += xv * b.z; acc[7] += xv * b.w;
  }
#pragma unroll
  for (int m = 32; m > 0; m >>= 1) {
#pragma unroll
    for (int e = 0; e < NE; e++) acc[e] += __shfl_xor(acc[e], m, 64);
  }
  if (lane < NE) logits[(size_t)t * NE + lane] = acc[lane];
  if (lane == 0) {
    int e0 = 0;
#pragma unroll
    for (int e = 1; e < NE; e++) if (acc[e] > acc[e0]) e0 = e;
    int e1 = (e0 == 0) ? 1 : 0;
#pragma unroll
    for (int e = 0; e < NE; e++) if (e != e0 && acc[e] > acc[e1]) e1 = e;
    float ex = expf(acc[e1] - acc[e0]);   // <= 1
    float w0 = 1.f / (1.f + ex);
    float w1 = ex / (1.f + ex);
    atomicAdd(&cnt[e0], 1);
    atomicAdd(&cnt[e1], 1);
    tokinfo[t] = make_int4(e0, e1, __float_as_int(w0), __float_as_int(w1));
  }
}

// cnt[0..7]=counts, cnt[8..15]=offsets, cnt[16..23]=scatter cursors
__global__ void offsets_kernel(int* __restrict__ cnt) {
  int o = 0;
  for (int e = 0; e < NE; e++) { cnt[8 + e] = o; o += cnt[e]; }
}

__global__ void scatter_kernel(const int4* __restrict__ tokinfo,
                               int* __restrict__ cnt,
                               int* __restrict__ row_tok,
                               int2* __restrict__ tok2row) {
  int t = blockIdx.x * blockDim.x + threadIdx.x;
  if (t >= T_TOK) return;
  int4 info = tokinfo[t];
  int p0 = atomicAdd(&cnt[16 + info.x], 1);
  int r0 = cnt[8 + info.x] + p0;
  row_tok[r0] = t;
  int p1 = atomicAdd(&cnt[16 + info.y], 1);
  int r1 = cnt[8 + info.y] + p1;
  row_tok[r1] = t;
  tok2row[t] = make_int2(r0, r1);
}

// ---------------- grouped GEMM 1: act = silu(x@Wg) * (x@Wu) ----------------
// 128x128 tile, BK=32, 4 waves, 16x16x32 MFMA (R4-proven conflict-free LDS
// read pattern). B (Wg/Wu) staged DIRECTLY from fp32 [E][H][I]: threads
// 0-127 stage Wg, 128-255 Wu; each thread 8 dwordx4 (4 cols x 8 k), register
// transpose + cvt, 4 ds_write_b128 into the slot-XOR layout. A via DMA from
// xbf. Pipeline: issue loads(k+1) -> vmcnt(2) -> write(k+1) -> compute(k)
// -> vmcnt(0) -> barrier.  launch_bounds (256,2): acc 128 + ~110 arch.
__launch_bounds__(256, 2)
__global__ void gemm1_kernel(const unsigned short* __restrict__ xbf,
                             const float* __restrict__ Wg,
                             const float* __restrict__ Wu,
                             unsigned short* __restrict__ act,
                             const int* __restrict__ row_tok,
                             const int* __restrict__ cnt) {
  const int f = blockIdx.x + 11 * (blockIdx.y + 32 * blockIdx.z);
  const int e = f & 7;
  const int rem = f >> 3;          // 0..351
  const int nt = rem >> 5;         // 0..10
  const int mt = rem & 31;         // 0..31
  const int c = cnt[e];
  if (mt * 128 >= c) return;
  const int off = cnt[8 + e];
  const int rowbase = off + mt * 128, rowend = off + c;
  const int i0 = nt * 128;
  __shared__ __align__(16) char smem[49152];
  const int tid = threadIdx.x;
  const int lane = tid & 63, w = tid >> 6;
  const int wr = w >> 1, wc = w & 1;

  // A-DMA addressing (R4 pattern)
  const int rr0 = w * 16 + (lane >> 2);
  const int rr1 = rr0 + 64;
  const int q0 = (lane & 3) ^ ((rr0 >> 1) & 3);
  const int q1 = (lane & 3) ^ ((rr1 >> 1) & 3);
  int g0 = rowbase + rr0; if (g0 > rowend - 1) g0 = rowend - 1;
  int g1 = rowbase + rr1; if (g1 > rowend - 1) g1 = rowend - 1;
  const size_t tokA0 = (size_t)row_tok[g0] * HD;
  const size_t tokA1 = (size_t)row_tok[g1] * HD;
  const int ldsA = w * 1024;

  // B reg-staging roles: bm=0 -> Wg, bm=1 -> Wu
  const int bm = tid >> 7;
  const int bt = tid & 127;
  const int bc = (bt & 31) * 4;        // col base within 128-tile
  const int bo = bt >> 5;              // k-octet 0..3
  const float* Wsel = (bm ? Wu : Wg) + (size_t)e * HD * NI + (i0 + bc);
  const int ldsB = 8192 + bm * 8192;

  f32x4 zero = {0.f, 0.f, 0.f, 0.f};
  f32x4 accg[4][4], accu[4][4];
#pragma unroll
  for (int a = 0; a < 4; a++)
#pragma unroll
    for (int b = 0; b < 4; b++) { accg[a][b] = zero; accu[a][b] = zero; }

  f32x4 breg[8];
  auto loadB = [&](int ks) {
    const float* src = Wsel + (size_t)(ks * 32 + bo * 8) * NI;
#pragma unroll
    for (int j = 0; j < 8; j++)
      breg[j] = *(const f32x4*)(src + (size_t)j * NI);
  };
  auto writeB = [&](int buf) {
    char* base = smem + buf * 24576 + ldsB;
#pragma unroll
    for (int ci = 0; ci < 4; ci++) {
      int n = bc + ci;
      bf16x8 v;
#pragma unroll
      for (int j = 0; j < 8; j++) v[j] = (__bf16)breg[j][ci];
      *(bf16x8*)(base + n * 64 + ((bo ^ ((n >> 1) & 3)) << 4)) = v;
    }
  };
  auto stageA = [&](int buf, int ks) {
    const int k0 = ks * 32;
    char* base = smem + buf * 24576;
    gload_lds16(xbf + tokA0 + k0 + q0 * 8, base + ldsA);
    gload_lds16(xbf + tokA1 + k0 + q1 * 8, base + ldsA + 4096);
  };

  const int rl = lane & 15, kslot = lane >> 4;
  auto compute = [&](int buf) {
    const char* base = smem + buf * 24576;
    bf16x8 af[4], bg[4], bu[4];
#pragma unroll
    for (int mi = 0; mi < 4; mi++) {
      int r = wr * 64 + mi * 16 + rl;
      int byt = r * 64 + ((kslot ^ ((r >> 1) & 3)) << 4);
      af[mi] = *(const bf16x8*)(base + byt);
    }
#pragma unroll
    for (int ni = 0; ni < 4; ni++) {
      int r = wc * 64 + ni * 16 + rl;
      int byt = r * 64 + ((kslot ^ ((r >> 1) & 3)) << 4);
      bg[ni] = *(const bf16x8*)(base + 8192 + byt);
      bu[ni] = *(const bf16x8*)(base + 16384 + byt);
    }
#pragma unroll
    for (int mi = 0; mi < 4; mi++)
#pragma unroll
      for (int ni = 0; ni < 4; ni++) {
        accg[mi][ni] = __builtin_amdgcn_mfma_f32_16x16x32_bf16(af[mi], bg[ni], accg[mi][ni], 0, 0, 0);
        accu[mi][ni] = __builtin_amdgcn_mfma_f32_16x16x32_bf16(af[mi], bu[ni], accu[mi][ni], 0, 0, 0);
      }
  };

  // prologue: tile 0 fully staged
  loadB(0);
  stageA(0, 0);
  S_WAITCNT_VMCNT(0);
  writeB(0);
  S_WAITCNT_LGKM0();
  wave_barrier();

  const int NKS = HD / 32;
  for (int ks = 0; ks < NKS; ks++) {
    const int cur = ks & 1;
    if (ks + 1 < NKS) {
      loadB(ks + 1);               // 8 vmem (oldest)
      stageA(cur ^ 1, ks + 1);     // 2 vmem (newest)
      S_WAITCNT_VMCNT(2);          // B regs ready; A-DMA(k+1) in flight
      writeB(cur ^ 1);
      compute(cur);
      S_WAITCNT_VMCNT(0);          // A-DMA(k+1) landed (covered by compute)
      S_WAITCNT_LGKM0();
      wave_barrier();
    } else {
      compute(cur);
    }
  }

  const int rh = lane >> 4;
#pragma unroll
  for (int mi = 0; mi < 4; mi++)
#pragma unroll
    for (int ni = 0; ni < 4; ni++)
#pragma unroll
      for (int j = 0; j < 4; j++) {
        int grow = rowbase + wr * 64 + mi * 16 + rh * 4 + j;
        if (grow < rowend) {
          int gcol = i0 + wc * 64 + ni * 16 + rl;
          float g = accg[mi][ni][j], u = accu[mi][ni][j];
          float val = g / (1.f + __expf(-g)) * u;
          act[(size_t)grow * NI + gcol] = f2bf(val);
        }
      }
}

// ---------------- grouped GEMM 2: y[row] = act[row] @ Wd  (no atomics) ------
// B (Wd) staged directly from fp32 [E][I][H]: thread = 4 cols x 4 k via
// 4 dwordx4, cvt, 4 ds_write_b64 (half-slots). A (act, bf16) via DMA.
__launch_bounds__(256, 3)
__global__ void gemm2_kernel(const unsigned short* __restrict__ act,
                             const float* __restrict__ Wd,
                             unsigned short* __restrict__ y,
                             const int* __restrict__ cnt) {
  const int f = blockIdx.x + 16 * (blockIdx.y + 32 * blockIdx.z);
  const int e = f & 7;
  const int rem = f >> 3;          // 0..511
  const int nt = rem >> 5;         // 0..15
  const int mt = rem & 31;         // 0..31
  const int c = cnt[e];
  if (mt * 128 >= c) return;
  const int off = cnt[8 + e];
  const int rowbase = off + mt * 128, rowend = off + c;
  const int n0 = nt * 128;
  __shared__ __align__(16) char smem[32768];
  const int tid = threadIdx.x;
  const int lane = tid & 63, w = tid >> 6;
  const int wr = w >> 1, wc = w & 1;

  const int rr0 = w * 16 + (lane >> 2);
  const int rr1 = rr0 + 64;
  const int q0 = (lane & 3) ^ ((rr0 >> 1) & 3);
  const int q1 = (lane & 3) ^ ((rr1 >> 1) & 3);
  int g0 = rowbase + rr0; if (g0 > rowend - 1) g0 = rowend - 1;
  int g1 = rowbase + rr1; if (g1 > rowend - 1) g1 = rowend - 1;
  const size_t aA0 = (size_t)g0 * NI;
  const size_t aA1 = (size_t)g1 * NI;
  const int ldsA = w * 1024;

  // B staging roles: 4 cols x 4 k per thread
  const int bc = (tid & 31) * 4;       // col base
  const int bq = tid >> 5;             // k-quad 0..7
  const float* Wsel = Wd + (size_t)e * NI * HD + (n0 + bc);

  f32x4 zero = {0.f, 0.f, 0.f, 0.f};
  f32x4 acc[4][4];
#pragma unroll
  for (int a = 0; a < 4; a++)
#pragma unroll
    for (int b = 0; b < 4; b++) acc[a][b] = zero;

  f32x4 breg[4];
  auto loadB = [&](int ks) {
    const float* src = Wsel + (size_t)(ks * 32 + bq * 4) * HD;
#pragma unroll
    for (int j = 0; j < 4; j++)
      breg[j] = *(const f32x4*)(src + (size_t)j * HD);
  };
  auto writeB = [&](int buf) {
    char* base = smem + buf * 16384 + 8192;
    const int o = bq >> 1, half = bq & 1;
#pragma unroll
    for (int ci = 0; ci < 4; ci++) {
      int n = bc + ci;
      bf16x4 v;
#pragma unroll
      for (int j = 0; j < 4; j++) v[j] = (__bf16)breg[j][ci];
      *(bf16x4*)(base + n * 64 + ((o ^ ((n >> 1) & 3)) << 4) + half * 8) = v;
    }
  };
  auto stageA = [&](int buf, int ks) {
    const int k0 = ks * 32;
    char* base = smem + buf * 16384;
    gload_lds16(act + aA0 + k0 + q0 * 8, base + ldsA);
    gload_lds16(act + aA1 + k0 + q1 * 8, base + ldsA + 4096);
  };

  const int rl = lane & 15, kslot = lane >> 4;
  auto compute = [&](int buf) {
    const char* base = smem + buf * 16384;
    bf16x8 af[4], bf[4];
#pragma unroll
    for (int mi = 0; mi < 4; mi++) {
      int r = wr * 64 + mi * 16 + rl;
      int byt = r * 64 + ((kslot ^ ((r >> 1) & 3)) << 4);
      af[mi] = *(const bf16x8*)(base + byt);
    }
#pragma unroll
    for (int ni = 0; ni < 4; ni++) {
      int r = wc * 64 + ni * 16 + rl;
      int byt = r * 64 + ((kslot ^ ((r >> 1) & 3)) << 4);
      bf[ni] = *(const bf16x8*)(base + 8192 + byt);
    }
#pragma unroll
    for (int mi = 0; mi < 4; mi++)
#pragma unroll
      for (int ni = 0; ni < 4; ni++)
        acc[mi][ni] = __builtin_amdgcn_mfma_f32_16x16x32_bf16(af[mi], bf[ni], acc[mi][ni], 0, 0, 0);
  };

  loadB(0);
  stageA(0, 0);
  S_WAITCNT_VMCNT(0);
  writeB(0);
  S_WAITCNT_LGKM0();
  wave_barrier();

  const int NKS = NI / 32;
  for (int ks = 0; ks < NKS; ks++) {
    const int cur = ks & 1;
    if (ks + 1 < NKS) {
      loadB(ks + 1);               // 4 vmem (oldest)
      stageA(cur ^ 1, ks + 1);     // 2 vmem (newest)
      S_WAITCNT_VMCNT(2);
      writeB(cur ^ 1);
      compute(cur);
      S_WAITCNT_VMCNT(0);
      S_WAITCNT_LGKM0();
      wave_barrier();
    } else {
      compute(cur);
    }
  }

  const int rh = lane >> 4;
#pragma unroll
  for (int mi = 0; mi < 4; mi++)
#pragma unroll
    for (int ni = 0; ni < 4; ni++)
#pragma unroll
      for (int j = 0; j < 4; j++) {
        int grow = rowbase + wr * 64 + mi * 16 + rh * 4 + j;
        if (grow < rowend) {
          int gcol = n0 + wc * 64 + ni * 16 + rl;
          y[(size_t)grow * HD + gcol] = f2bf(acc[mi][ni][j]);
        }
      }
}

// ---------------- combine: out[t] = w0*y[r0] + w1*y[r1] ----------------
__global__ void combine_kernel(const unsigned short* __restrict__ y,
                               const int2* __restrict__ tok2row,
                               const int4* __restrict__ tokinfo,
                               float* __restrict__ out) {
  int t = blockIdx.x, tid = threadIdx.x;
  int2 rr = tok2row[t];
  int4 info = tokinfo[t];
  float w0 = __int_as_float(info.z), w1 = __int_as_float(info.w);
  ushort8 a = ((const ushort8*)(y + (size_t)rr.x * HD))[tid];
  ushort8 b = ((const ushort8*)(y + (size_t)rr.y * HD))[tid];
  float4 o0, o1;
  o0.x = w0 * bf2f(a[0]) + w1 * bf2f(b[0]);
  o0.y = w0 * bf2f(a[1]) + w1 * bf2f(b[1]);
  o0.z = w0 * bf2f(a[2]) + w1 * bf2f(b[2]);
  o0.w = w0 * bf2f(a[3]) + w1 * bf2f(b[3]);
  o1.x = w0 * bf2f(a[4]) + w1 * bf2f(b[4]);
  o1.y = w0 * bf2f(a[5]) + w1 * bf2f(b[5]);
  o1.z = w0 * bf2f(a[6]) + w1 * bf2f(b[6]);
  o1.w = w0 * bf2f(a[7]) + w1 * bf2f(b[7]);
  float4* op = (float4*)(out + (size_t)t * HD + tid * 8);
  op[0] = o0; op[1] = o1;
}

// ---------------- launch ----------------
extern "C" void kernel_launch(void* const* d_in, const int* in_sizes, int n_in,
                              void* d_out, int out_size, void* d_ws, size_t ws_size,
                              hipStream_t stream) {
  const float* x  = (const float*)d_in[0];
  const float* Wr = (const float*)d_in[1];
  const float* Wg = (const float*)d_in[2];
  const float* Wu = (const float*)d_in[3];
  const float* Wd = (const float*)d_in[4];
  float* out = (float*)d_out;
  char* ws = (char*)d_ws;

  // ws layout (bytes)
  unsigned short* xbf = (unsigned short*)(ws);                 // 16,777,216
  unsigned short* act = (unsigned short*)(ws + 16777216);      // 23,068,672
  unsigned short* yb  = (unsigned short*)(ws + 39845888);      // 33,554,432
  int4*  tokinfo      = (int4*)(ws + 73400320);                // 65,536
  int*   row_tok      = (int*)(ws + 73465856);                 // 32,768
  int2*  tok2row      = (int2*)(ws + 73498624);                // 32,768
  int*   cnt          = (int*)(ws + 73531392);                 // 96

  hipMemsetAsync(cnt, 0, 96, stream);

  router_kernel<<<T_TOK / 4, 256, 0, stream>>>(x, Wr, out + (size_t)T_TOK * HD, xbf, tokinfo, cnt);
  offsets_kernel<<<1, 1, 0, stream>>>(cnt);
  scatter_kernel<<<T_TOK / 256, 256, 0, stream>>>(tokinfo, cnt, row_tok, tok2row);

  gemm1_kernel<<<dim3(11, 32, NE), 256, 0, stream>>>(xbf, Wg, Wu, act, row_tok, cnt);
  gemm2_kernel<<<dim3(16, 32, NE), 256, 0, stream>>>(act, Wd, yb, cnt);
  combine_kernel<<<T_TOK, 256, 0, stream>>>(yb, tok2row, tokinfo, out);
}

// Round 7
// 518.971 us; speedup vs baseline: 1.1473x; 1.1473x over previous
//
#include <hip/hip_runtime.h>

#define T_TOK 4096
#define HD 2048
#define NE 8
#define NI 1408

typedef __bf16 bf16x8 __attribute__((ext_vector_type(8)));
typedef float f32x4 __attribute__((ext_vector_type(4)));
typedef unsigned short ushort8 __attribute__((ext_vector_type(8)));

#define S_WAITCNT_VMCNT(n) asm volatile("s_waitcnt vmcnt(" #n ")" ::: "memory")
__device__ __forceinline__ void wave_barrier() {
  asm volatile("" ::: "memory");
  __builtin_amdgcn_s_barrier();
  asm volatile("" ::: "memory");
}

__device__ __forceinline__ unsigned short f2bf(float f) {
  unsigned int u = __float_as_uint(f);
  u += 0x7FFFu + ((u >> 16) & 1u);
  return (unsigned short)(u >> 16);
}
__device__ __forceinline__ float bf2f(unsigned short u) {
  return __uint_as_float((unsigned int)u << 16);
}

__device__ __forceinline__ void gload_lds16(const void* g, void* l) {
  __builtin_amdgcn_global_load_lds(
      (const __attribute__((address_space(1))) unsigned int*)g,
      (__attribute__((address_space(3))) unsigned int*)l, 16, 0, 0);
}

// src [E][R][C] f32 -> dst [E][C][R] bf16.  64x64 tile, 256 threads.
// dual=1: blockIdx.z&1 selects (srcA,dstA)/(srcB,dstB) (Wg+Wu in one launch).
__global__ void transpose_cvt2_kernel(const float* __restrict__ srcA,
                                      unsigned short* __restrict__ dstA,
                                      const float* __restrict__ srcB,
                                      unsigned short* __restrict__ dstB,
                                      int R, int C, int dual) {
  __shared__ float tile[64][65];
  int z = blockIdx.z;
  int e = dual ? (z >> 1) : z;
  const float* sp = (dual && (z & 1)) ? srcB : srcA;
  unsigned short* dp = (dual && (z & 1)) ? dstB : dstA;
  int r0 = blockIdx.y * 64, c0 = blockIdx.x * 64;
  const float* s = sp + (size_t)e * R * C;
  unsigned short* d = dp + (size_t)e * R * C;
  int tid = threadIdx.x;
  int lr = tid >> 4, lc = (tid & 15) * 4;
#pragma unroll
  for (int p = 0; p < 4; p++) {
    int r = lr + p * 16;
    float4 v = *(const float4*)(s + (size_t)(r0 + r) * C + c0 + lc);
    tile[r][lc] = v.x; tile[r][lc + 1] = v.y;
    tile[r][lc + 2] = v.z; tile[r][lc + 3] = v.w;
  }
  __syncthreads();
  int rbase = (tid & 7) * 8, crel = tid >> 3;   // crel 0..31
#pragma unroll
  for (int p = 0; p < 2; p++) {
    int c = p * 32 + crel;
    ushort8 o;
#pragma unroll
    for (int j = 0; j < 8; j++) o[j] = f2bf(tile[rbase + j][c]);
    *(ushort8*)(d + (size_t)(c0 + c) * R + r0 + rbase) = o;
  }
}

// ---------------- routing (also emits x in bf16) ----------------
__global__ void router_kernel(const float* __restrict__ x,
                              const float* __restrict__ Wr,
                              float* __restrict__ logits,
                              unsigned short* __restrict__ xbf,
                              int4* __restrict__ tokinfo,
                              int* __restrict__ cnt) {
  int wv = threadIdx.x >> 6, lane = threadIdx.x & 63;
  int t = blockIdx.x * 4 + wv;
  const float* xr = x + (size_t)t * HD;
  unsigned short* xbr = xbf + (size_t)t * HD;
  float acc[NE];
#pragma unroll
  for (int e = 0; e < NE; e++) acc[e] = 0.f;
  for (int hi = 0; hi < HD / 64; hi++) {
    int h = hi * 64 + lane;
    float xv = xr[h];
    xbr[h] = f2bf(xv);
    const float4* w4 = (const float4*)(Wr + (size_t)h * NE);
    float4 a = w4[0], b = w4[1];
    acc[0] += xv * a.x; acc[1] += xv * a.y; acc[2] += xv * a.z; acc[3] += xv * a.w;
    acc[4] += xv * b.x; acc[5] += xv * b.y; acc[6] += xv * b.z; acc[7] += xv * b.w;
  }
#pragma unroll
  for (int m = 32; m > 0; m >>= 1) {
#pragma unroll
    for (int e = 0; e < NE; e++) acc[e] += __shfl_xor(acc[e], m, 64);
  }
  if (lane < NE) logits[(size_t)t * NE + lane] = acc[lane];
  if (lane == 0) {
    int e0 = 0;
#pragma unroll
    for (int e = 1; e < NE; e++) if (acc[e] > acc[e0]) e0 = e;
    int e1 = (e0 == 0) ? 1 : 0;
#pragma unroll
    for (int e = 0; e < NE; e++) if (e != e0 && acc[e] > acc[e1]) e1 = e;
    float ex = expf(acc[e1] - acc[e0]);   // <= 1
    float w0 = 1.f / (1.f + ex);
    float w1 = ex / (1.f + ex);
    atomicAdd(&cnt[e0], 1);
    atomicAdd(&cnt[e1], 1);
    tokinfo[t] = make_int4(e0, e1, __float_as_int(w0), __float_as_int(w1));
  }
}

// cnt[0..7]=counts, [8..15]=offsets, [16..23]=scatter cursors,
// [24]=worklist len, [25]=gemm1 queue, [26]=gemm2 queue.
// wl[i] = (e<<16)|mt for every non-empty 128-row m-tile.
__global__ void offsets_kernel(int* __restrict__ cnt, int* __restrict__ wl) {
  int o = 0, n = 0;
  for (int e = 0; e < NE; e++) {
    cnt[8 + e] = o;
    int c = cnt[e];
    o += c;
    int mts = (c + 127) >> 7;
    for (int mt = 0; mt < mts; mt++) wl[n++] = (e << 16) | mt;
  }
  cnt[24] = n;
}

__global__ void scatter_kernel(const int4* __restrict__ tokinfo,
                               int* __restrict__ cnt,
                               int* __restrict__ row_tok,
                               int2* __restrict__ tok2row) {
  int t = blockIdx.x * blockDim.x + threadIdx.x;
  if (t >= T_TOK) return;
  int4 info = tokinfo[t];
  int p0 = atomicAdd(&cnt[16 + info.x], 1);
  int r0 = cnt[8 + info.x] + p0;
  row_tok[r0] = t;
  int p1 = atomicAdd(&cnt[16 + info.y], 1);
  int r1 = cnt[8 + info.y] + p1;
  row_tok[r1] = t;
  tok2row[t] = make_int2(r0, r1);
}

// ---------------- grouped GEMM 1: act = silu(x@Wg) * (x@Wu) ----------------
// R4-proven body (128x128, BK=32, 16x16x32, conflict-free XOR slots, counted
// vmcnt) wrapped in a persistent work-stealing loop: blocks pop flat tile
// indices (nt-outer: ~8 consecutive pops share one (e,nt) B-panel).
// launch_bounds (256,2): 128 acc + ~105 VGPR unified (R2 spill lesson).
__launch_bounds__(256, 2)
__global__ void gemm1_kernel(const unsigned short* __restrict__ xbf,
                             const unsigned short* __restrict__ Wgt,
                             const unsigned short* __restrict__ Wut,
                             unsigned short* __restrict__ act,
                             const int* __restrict__ row_tok,
                             int* __restrict__ cnt,
                             const int* __restrict__ wl) {
  __shared__ __align__(16) char smem[49152];
  __shared__ int sidx;
  const int tid = threadIdx.x;
  const int lane = tid & 63, w = tid >> 6;
  const int wr = w >> 1, wc = w & 1;
  const int nwl = cnt[24];
  const int total = nwl * (NI / 128);
  const int ldsA = w * 1024;
  const int rl = lane & 15, kslot = lane >> 4;
  const int rr0 = w * 16 + (lane >> 2);
  const int rr1 = rr0 + 64;
  const int q0 = (lane & 3) ^ ((rr0 >> 1) & 3);
  const int q1 = (lane & 3) ^ ((rr1 >> 1) & 3);

  for (;;) {
    if (tid == 0) sidx = atomicAdd(&cnt[25], 1);
    __syncthreads();                 // broadcast idx; fences prev tile's LDS
    const int idx = sidx;
    if (idx >= total) break;
    const int nt = idx / nwl;
    const int went = wl[idx - nt * nwl];
    const int e = went >> 16, mt = went & 0xffff;
    const int c = cnt[e];
    const int off = cnt[8 + e];
    const int rowbase = off + mt * 128, rowend = off + c;
    const int i0 = nt * 128;

    int g0 = rowbase + rr0; if (g0 > rowend - 1) g0 = rowend - 1;
    int g1 = rowbase + rr1; if (g1 > rowend - 1) g1 = rowend - 1;
    const size_t tokA0 = (size_t)row_tok[g0] * HD;
    const size_t tokA1 = (size_t)row_tok[g1] * HD;
    const size_t bB0 = ((size_t)e * NI + i0 + rr0) * HD;
    const size_t bB1 = ((size_t)e * NI + i0 + rr1) * HD;

    f32x4 zero = {0.f, 0.f, 0.f, 0.f};
    f32x4 accg[4][4], accu[4][4];
#pragma unroll
    for (int a = 0; a < 4; a++)
#pragma unroll
      for (int b = 0; b < 4; b++) { accg[a][b] = zero; accu[a][b] = zero; }

    auto stage = [&](int buf, int ks) {
      const int k0 = ks * 32;
      char* base = smem + buf * 24576;
      gload_lds16(xbf + tokA0 + k0 + q0 * 8, base + ldsA);
      gload_lds16(xbf + tokA1 + k0 + q1 * 8, base + ldsA + 4096);
      gload_lds16(Wgt + bB0 + k0 + q0 * 8, base + 8192 + ldsA);
      gload_lds16(Wgt + bB1 + k0 + q1 * 8, base + 8192 + ldsA + 4096);
      gload_lds16(Wut + bB0 + k0 + q0 * 8, base + 16384 + ldsA);
      gload_lds16(Wut + bB1 + k0 + q1 * 8, base + 16384 + ldsA + 4096);
    };
    auto compute = [&](int buf) {
      const char* base = smem + buf * 24576;
      bf16x8 af[4], bg[4], bu[4];
#pragma unroll
      for (int mi = 0; mi < 4; mi++) {
        int r = wr * 64 + mi * 16 + rl;
        int byt = r * 64 + ((kslot ^ ((r >> 1) & 3)) << 4);
        af[mi] = *(const bf16x8*)(base + byt);
      }
#pragma unroll
      for (int ni = 0; ni < 4; ni++) {
        int r = wc * 64 + ni * 16 + rl;
        int byt = r * 64 + ((kslot ^ ((r >> 1) & 3)) << 4);
        bg[ni] = *(const bf16x8*)(base + 8192 + byt);
        bu[ni] = *(const bf16x8*)(base + 16384 + byt);
      }
#pragma unroll
      for (int mi = 0; mi < 4; mi++)
#pragma unroll
        for (int ni = 0; ni < 4; ni++) {
          accg[mi][ni] = __builtin_amdgcn_mfma_f32_16x16x32_bf16(af[mi], bg[ni], accg[mi][ni], 0, 0, 0);
          accu[mi][ni] = __builtin_amdgcn_mfma_f32_16x16x32_bf16(af[mi], bu[ni], accu[mi][ni], 0, 0, 0);
        }
    };

    stage(0, 0);
    const int NKS = HD / 32;
    int ks = 0;
    for (; ks < NKS - 1; ks++) {
      stage((ks + 1) & 1, ks + 1);
      S_WAITCNT_VMCNT(6);    // tile ks complete; tile ks+1 stays in flight
      wave_barrier();
      compute(ks & 1);
      wave_barrier();
    }
    S_WAITCNT_VMCNT(0);
    wave_barrier();
    compute(ks & 1);

    const int rh = lane >> 4;
#pragma unroll
    for (int mi = 0; mi < 4; mi++)
#pragma unroll
      for (int ni = 0; ni < 4; ni++)
#pragma unroll
        for (int j = 0; j < 4; j++) {
          int grow = rowbase + wr * 64 + mi * 16 + rh * 4 + j;
          if (grow < rowend) {
            int gcol = i0 + wc * 64 + ni * 16 + rl;
            float g = accg[mi][ni][j], u = accu[mi][ni][j];
            float val = g / (1.f + __expf(-g)) * u;
            act[(size_t)grow * NI + gcol] = f2bf(val);
          }
        }
  }
}

// ---------------- grouped GEMM 2: y[row] = act[row] @ Wd  (no atomics) ------
// launch_bounds (256,4): 64 acc + ~60 VGPR = ~124 <= 128 cap -> 4 blocks/CU.
// Tripwire: if WRITE_SIZE >> 32 MB it spilled -> revert to 3.
__launch_bounds__(256, 4)
__global__ void gemm2_kernel(const unsigned short* __restrict__ act,
                             const unsigned short* __restrict__ Wdt,
                             unsigned short* __restrict__ y,
                             int* __restrict__ cnt,
                             const int* __restrict__ wl) {
  __shared__ __align__(16) char smem[32768];
  __shared__ int sidx;
  const int tid = threadIdx.x;
  const int lane = tid & 63, w = tid >> 6;
  const int wr = w >> 1, wc = w & 1;
  const int nwl = cnt[24];
  const int total = nwl * (HD / 128);
  const int ldsA = w * 1024;
  const int rl = lane & 15, kslot = lane >> 4;
  const int rr0 = w * 16 + (lane >> 2);
  const int rr1 = rr0 + 64;
  const int q0 = (lane & 3) ^ ((rr0 >> 1) & 3);
  const int q1 = (lane & 3) ^ ((rr1 >> 1) & 3);

  for (;;) {
    if (tid == 0) sidx = atomicAdd(&cnt[26], 1);
    __syncthreads();
    const int idx = sidx;
    if (idx >= total) break;
    const int nt = idx / nwl;
    const int went = wl[idx - nt * nwl];
    const int e = went >> 16, mt = went & 0xffff;
    const int c = cnt[e];
    const int off = cnt[8 + e];
    const int rowbase = off + mt * 128, rowend = off + c;
    const int n0 = nt * 128;

    int g0 = rowbase + rr0; if (g0 > rowend - 1) g0 = rowend - 1;
    int g1 = rowbase + rr1; if (g1 > rowend - 1) g1 = rowend - 1;
    const size_t aA0 = (size_t)g0 * NI;
    const size_t aA1 = (size_t)g1 * NI;
    const size_t bB0 = ((size_t)e * HD + n0 + rr0) * NI;
    const size_t bB1 = ((size_t)e * HD + n0 + rr1) * NI;

    f32x4 zero = {0.f, 0.f, 0.f, 0.f};
    f32x4 acc[4][4];
#pragma unroll
    for (int a = 0; a < 4; a++)
#pragma unroll
      for (int b = 0; b < 4; b++) acc[a][b] = zero;

    auto stage = [&](int buf, int ks) {
      const int k0 = ks * 32;
      char* base = smem + buf * 16384;
      gload_lds16(act + aA0 + k0 + q0 * 8, base + ldsA);
      gload_lds16(act + aA1 + k0 + q1 * 8, base + ldsA + 4096);
      gload_lds16(Wdt + bB0 + k0 + q0 * 8, base + 8192 + ldsA);
      gload_lds16(Wdt + bB1 + k0 + q1 * 8, base + 8192 + ldsA + 4096);
    };
    auto compute = [&](int buf) {
      const char* base = smem + buf * 16384;
      bf16x8 af[4], bf[4];
#pragma unroll
      for (int mi = 0; mi < 4; mi++) {
        int r = wr * 64 + mi * 16 + rl;
        int byt = r * 64 + ((kslot ^ ((r >> 1) & 3)) << 4);
        af[mi] = *(const bf16x8*)(base + byt);
      }
#pragma unroll
      for (int ni = 0; ni < 4; ni++) {
        int r = wc * 64 + ni * 16 + rl;
        int byt = r * 64 + ((kslot ^ ((r >> 1) & 3)) << 4);
        bf[ni] = *(const bf16x8*)(base + 8192 + byt);
      }
#pragma unroll
      for (int mi = 0; mi < 4; mi++)
#pragma unroll
        for (int ni = 0; ni < 4; ni++)
          acc[mi][ni] = __builtin_amdgcn_mfma_f32_16x16x32_bf16(af[mi], bf[ni], acc[mi][ni], 0, 0, 0);
    };

    stage(0, 0);
    const int NKS = NI / 32;
    int ks = 0;
    for (; ks < NKS - 1; ks++) {
      stage((ks + 1) & 1, ks + 1);
      S_WAITCNT_VMCNT(4);
      wave_barrier();
      compute(ks & 1);
      wave_barrier();
    }
    S_WAITCNT_VMCNT(0);
    wave_barrier();
    compute(ks & 1);

    const int rh = lane >> 4;
#pragma unroll
    for (int mi = 0; mi < 4; mi++)
#pragma unroll
      for (int ni = 0; ni < 4; ni++)
#pragma unroll
        for (int j = 0; j < 4; j++) {
          int grow = rowbase + wr * 64 + mi * 16 + rh * 4 + j;
          if (grow < rowend) {
            int gcol = n0 + wc * 64 + ni * 16 + rl;
            y[(size_t)grow * HD + gcol] = f2bf(acc[mi][ni][j]);
          }
        }
  }
}

// ---------------- combine: out[t] = w0*y[r0] + w1*y[r1] ----------------
__global__ void combine_kernel(const unsigned short* __restrict__ y,
                               const int2* __restrict__ tok2row,
                               const int4* __restrict__ tokinfo,
                               float* __restrict__ out) {
  int t = blockIdx.x, tid = threadIdx.x;
  int2 rr = tok2row[t];
  int4 info = tokinfo[t];
  float w0 = __int_as_float(info.z), w1 = __int_as_float(info.w);
  ushort8 a = ((const ushort8*)(y + (size_t)rr.x * HD))[tid];
  ushort8 b = ((const ushort8*)(y + (size_t)rr.y * HD))[tid];
  float4 o0, o1;
  o0.x = w0 * bf2f(a[0]) + w1 * bf2f(b[0]);
  o0.y = w0 * bf2f(a[1]) + w1 * bf2f(b[1]);
  o0.z = w0 * bf2f(a[2]) + w1 * bf2f(b[2]);
  o0.w = w0 * bf2f(a[3]) + w1 * bf2f(b[3]);
  o1.x = w0 * bf2f(a[4]) + w1 * bf2f(b[4]);
  o1.y = w0 * bf2f(a[5]) + w1 * bf2f(b[5]);
  o1.z = w0 * bf2f(a[6]) + w1 * bf2f(b[6]);
  o1.w = w0 * bf2f(a[7]) + w1 * bf2f(b[7]);
  float4* op = (float4*)(out + (size_t)t * HD + tid * 8);
  op[0] = o0; op[1] = o1;
}

// ---------------- launch ----------------
extern "C" void kernel_launch(void* const* d_in, const int* in_sizes, int n_in,
                              void* d_out, int out_size, void* d_ws, size_t ws_size,
                              hipStream_t stream) {
  const float* x  = (const float*)d_in[0];
  const float* Wr = (const float*)d_in[1];
  const float* Wg = (const float*)d_in[2];
  const float* Wu = (const float*)d_in[3];
  const float* Wd = (const float*)d_in[4];
  float* out = (float*)d_out;
  char* ws = (char*)d_ws;

  // ws layout (bytes)
  unsigned short* xbf = (unsigned short*)(ws);                 // 16,777,216
  unsigned short* Wgt = (unsigned short*)(ws + 16777216);      // 46,137,344
  unsigned short* Wut = (unsigned short*)(ws + 62914560);      // 46,137,344
  unsigned short* Wdt = (unsigned short*)(ws + 109051904);     // 46,137,344
  unsigned short* act = (unsigned short*)(ws + 155189248);     // 23,068,672
  // y aliases Wgt: gemm1 (last reader of Wgt) completes before gemm2 writes y.
  unsigned short* yb  = (unsigned short*)(ws + 16777216);      // 33,554,432
  int4*  tokinfo      = (int4*)(ws + 178257920);               // 65,536
  int*   row_tok      = (int*)(ws + 178323456);                // 32,768
  int2*  tok2row      = (int2*)(ws + 178356224);               // 32,768
  int*   cnt          = (int*)(ws + 178388992);                // 128
  int*   wl           = (int*)(ws + 178389120);                // 1,024

  hipMemsetAsync(cnt, 0, 128, stream);

  router_kernel<<<T_TOK / 4, 256, 0, stream>>>(x, Wr, out + (size_t)T_TOK * HD, xbf, tokinfo, cnt);
  offsets_kernel<<<1, 1, 0, stream>>>(cnt, wl);
  scatter_kernel<<<T_TOK / 256, 256, 0, stream>>>(tokinfo, cnt, row_tok, tok2row);

  transpose_cvt2_kernel<<<dim3(NI / 64, HD / 64, NE * 2), 256, 0, stream>>>(
      Wg, Wgt, Wu, Wut, HD, NI, 1);
  transpose_cvt2_kernel<<<dim3(HD / 64, NI / 64, NE), 256, 0, stream>>>(
      Wd, Wdt, nullptr, nullptr, NI, HD, 0);

  gemm1_kernel<<<512, 256, 0, stream>>>(xbf, Wgt, Wut, act, row_tok, cnt, wl);
  gemm2_kernel<<<1024, 256, 0, stream>>>(act, Wdt, yb, cnt, wl);
  combine_kernel<<<T_TOK, 256, 0, stream>>>(yb, tok2row, tokinfo, out);
}

// Round 8
// 472.801 us; speedup vs baseline: 1.2593x; 1.0977x over previous
//
#include <hip/hip_runtime.h>

#define T_TOK 4096
#define HD 2048
#define NE 8
#define NI 1408

typedef __bf16 bf16x8 __attribute__((ext_vector_type(8)));
typedef float f32x4 __attribute__((ext_vector_type(4)));
typedef unsigned short ushort8 __attribute__((ext_vector_type(8)));

#define S_WAITCNT_VMCNT(n) asm volatile("s_waitcnt vmcnt(" #n ")" ::: "memory")
__device__ __forceinline__ void wave_barrier() {
  asm volatile("" ::: "memory");
  __builtin_amdgcn_s_barrier();
  asm volatile("" ::: "memory");
}

__device__ __forceinline__ unsigned short f2bf(float f) {
  unsigned int u = __float_as_uint(f);
  u += 0x7FFFu + ((u >> 16) & 1u);
  return (unsigned short)(u >> 16);
}
__device__ __forceinline__ float bf2f(unsigned short u) {
  return __uint_as_float((unsigned int)u << 16);
}

__device__ __forceinline__ void gload_lds16(const void* g, void* l) {
  __builtin_amdgcn_global_load_lds(
      (const __attribute__((address_space(1))) unsigned int*)g,
      (__attribute__((address_space(3))) unsigned int*)l, 16, 0, 0);
}

// src [E][R][C] f32 -> dst [E][C][R] bf16.  128(r) x 64(c) tile, 256 threads,
// register-only 8x4 transpose per thread, NO LDS (R4's LDS version was
// LDS-instruction-bound at ~2.5 TB/s).  Reads: 8x float4, 16 consecutive
// lanes = 256B. Writes: 4x ushort8; 4 consecutive-ti lanes = 64B sector.
// dual=1: blockIdx.z&1 selects (srcA,dstA)/(srcB,dstB).
__global__ void transpose_cvt2_kernel(const float* __restrict__ srcA,
                                      unsigned short* __restrict__ dstA,
                                      const float* __restrict__ srcB,
                                      unsigned short* __restrict__ dstB,
                                      int R, int C, int dual) {
  int z = blockIdx.z;
  int e = dual ? (z >> 1) : z;
  const float* sp = (dual && (z & 1)) ? srcB : srcA;
  unsigned short* dp = (dual && (z & 1)) ? dstB : dstA;
  int c0 = blockIdx.x * 64, r0 = blockIdx.y * 128;
  const float* s = sp + (size_t)e * R * C;
  unsigned short* d = dp + (size_t)e * R * C;
  int tid = threadIdx.x;
  int tj = tid & 15, ti = tid >> 4;
  const float* sb = s + (size_t)(r0 + ti * 8) * C + c0 + tj * 4;
  f32x4 v[8];
#pragma unroll
  for (int r = 0; r < 8; r++) v[r] = *(const f32x4*)(sb + (size_t)r * C);
  unsigned short* db = d + (size_t)(c0 + tj * 4) * R + r0 + ti * 8;
#pragma unroll
  for (int cc = 0; cc < 4; cc++) {
    ushort8 o;
#pragma unroll
    for (int r = 0; r < 8; r++) o[r] = f2bf(v[r][cc]);
    *(ushort8*)(db + (size_t)cc * R) = o;
  }
}

// ---------------- routing (also emits x in bf16), float4-vectorized --------
__global__ void router_kernel(const float* __restrict__ x,
                              const float* __restrict__ Wr,
                              float* __restrict__ logits,
                              unsigned short* __restrict__ xbf,
                              int4* __restrict__ tokinfo,
                              int* __restrict__ cnt) {
  int wv = threadIdx.x >> 6, lane = threadIdx.x & 63;
  int t = blockIdx.x * 4 + wv;
  const float* xr = x + (size_t)t * HD;
  unsigned short* xbr = xbf + (size_t)t * HD;
  float acc[NE];
#pragma unroll
  for (int e = 0; e < NE; e++) acc[e] = 0.f;
  for (int hi = 0; hi < HD / 256; hi++) {
    int h = hi * 256 + lane * 4;
    f32x4 xv = *(const f32x4*)(xr + h);
    ushort4 o = { f2bf(xv[0]), f2bf(xv[1]), f2bf(xv[2]), f2bf(xv[3]) };
    *(ushort4*)(xbr + h) = o;
#pragma unroll
    for (int j = 0; j < 4; j++) {
      const float4* w4 = (const float4*)(Wr + (size_t)(h + j) * NE);
      float4 a = w4[0], b = w4[1];
      float xs = xv[j];
      acc[0] += xs * a.x; acc[1] += xs * a.y; acc[2] += xs * a.z; acc[3] += xs * a.w;
      acc[4] += xs * b.x; acc[5] += xs * b.y; acc[6] += xs * b.z; acc[7] += xs * b.w;
    }
  }
#pragma unroll
  for (int m = 32; m > 0; m >>= 1) {
#pragma unroll
    for (int e = 0; e < NE; e++) acc[e] += __shfl_xor(acc[e], m, 64);
  }
  if (lane < NE) logits[(size_t)t * NE + lane] = acc[lane];
  if (lane == 0) {
    int e0 = 0;
#pragma unroll
    for (int e = 1; e < NE; e++) if (acc[e] > acc[e0]) e0 = e;
    int e1 = (e0 == 0) ? 1 : 0;
#pragma unroll
    for (int e = 0; e < NE; e++) if (e != e0 && acc[e] > acc[e1]) e1 = e;
    float ex = expf(acc[e1] - acc[e0]);   // <= 1
    float w0 = 1.f / (1.f + ex);
    float w1 = ex / (1.f + ex);
    atomicAdd(&cnt[e0], 1);
    atomicAdd(&cnt[e1], 1);
    tokinfo[t] = make_int4(e0, e1, __float_as_int(w0), __float_as_int(w1));
  }
}

// cnt[0..7]=counts, cnt[8..15]=offsets, cnt[16..23]=scatter cursors
__global__ void offsets_kernel(int* __restrict__ cnt) {
  int o = 0;
  for (int e = 0; e < NE; e++) { cnt[8 + e] = o; o += cnt[e]; }
}

__global__ void scatter_kernel(const int4* __restrict__ tokinfo,
                               int* __restrict__ cnt,
                               int* __restrict__ row_tok,
                               int2* __restrict__ tok2row) {
  int t = blockIdx.x * blockDim.x + threadIdx.x;
  if (t >= T_TOK) return;
  int4 info = tokinfo[t];
  int p0 = atomicAdd(&cnt[16 + info.x], 1);
  int r0 = cnt[8 + info.x] + p0;
  row_tok[r0] = t;
  int p1 = atomicAdd(&cnt[16 + info.y], 1);
  int r1 = cnt[8 + info.y] + p1;
  row_tok[r1] = t;
  tok2row[t] = make_int2(r0, r1);
}

// ---------------- grouped GEMM 1: act = silu(x@Wg) * (x@Wu) ----------------
// R4-proven: 128x128 tile, BK=32, 4 waves, 16x16x32 MFMA, conflict-free XOR
// slots, counted-vmcnt pipeline, static XCD swizzle expert = flat_id & 7
// (R7 showed dynamic worklist loses L2 affinity: FETCH 111->205 MB).
// launch_bounds MUST stay (256,2): 128 acc + ~100 VGPR (R2 spill lesson).
__launch_bounds__(256, 2)
__global__ void gemm1_kernel(const unsigned short* __restrict__ xbf,
                             const unsigned short* __restrict__ Wgt,
                             const unsigned short* __restrict__ Wut,
                             unsigned short* __restrict__ act,
                             const int* __restrict__ row_tok,
                             const int* __restrict__ cnt) {
  const int f = blockIdx.x + 11 * (blockIdx.y + 32 * blockIdx.z);
  const int e = f & 7;
  const int rem = f >> 3;          // 0..351
  const int nt = rem >> 5;         // 0..10
  const int mt = rem & 31;         // 0..31
  const int c = cnt[e];
  if (mt * 128 >= c) return;
  const int off = cnt[8 + e];
  const int rowbase = off + mt * 128, rowend = off + c;
  const int i0 = nt * 128;
  __shared__ __align__(16) char smem[49152];
  const int lane = threadIdx.x & 63, w = threadIdx.x >> 6;
  const int wr = w >> 1, wc = w & 1;

  const int rr0 = w * 16 + (lane >> 2);
  const int rr1 = rr0 + 64;
  const int q0 = (lane & 3) ^ ((rr0 >> 1) & 3);
  const int q1 = (lane & 3) ^ ((rr1 >> 1) & 3);
  int g0 = rowbase + rr0; if (g0 > rowend - 1) g0 = rowend - 1;
  int g1 = rowbase + rr1; if (g1 > rowend - 1) g1 = rowend - 1;
  const size_t tokA0 = (size_t)row_tok[g0] * HD;
  const size_t tokA1 = (size_t)row_tok[g1] * HD;
  const size_t bB0 = ((size_t)e * NI + i0 + rr0) * HD;
  const size_t bB1 = ((size_t)e * NI + i0 + rr1) * HD;
  const int ldsA = w * 1024;

  f32x4 zero = {0.f, 0.f, 0.f, 0.f};
  f32x4 accg[4][4], accu[4][4];
#pragma unroll
  for (int a = 0; a < 4; a++)
#pragma unroll
    for (int b = 0; b < 4; b++) { accg[a][b] = zero; accu[a][b] = zero; }

  auto stage = [&](int buf, int ks) {
    const int k0 = ks * 32;
    char* base = smem + buf * 24576;
    gload_lds16(xbf + tokA0 + k0 + q0 * 8, base + ldsA);
    gload_lds16(xbf + tokA1 + k0 + q1 * 8, base + ldsA + 4096);
    gload_lds16(Wgt + bB0 + k0 + q0 * 8, base + 8192 + ldsA);
    gload_lds16(Wgt + bB1 + k0 + q1 * 8, base + 8192 + ldsA + 4096);
    gload_lds16(Wut + bB0 + k0 + q0 * 8, base + 16384 + ldsA);
    gload_lds16(Wut + bB1 + k0 + q1 * 8, base + 16384 + ldsA + 4096);
  };
  const int rl = lane & 15, kslot = lane >> 4;
  auto compute = [&](int buf) {
    const char* base = smem + buf * 24576;
    bf16x8 af[4], bg[4], bu[4];
#pragma unroll
    for (int mi = 0; mi < 4; mi++) {
      int r = wr * 64 + mi * 16 + rl;
      int byt = r * 64 + ((kslot ^ ((r >> 1) & 3)) << 4);
      af[mi] = *(const bf16x8*)(base + byt);
    }
#pragma unroll
    for (int ni = 0; ni < 4; ni++) {
      int r = wc * 64 + ni * 16 + rl;
      int byt = r * 64 + ((kslot ^ ((r >> 1) & 3)) << 4);
      bg[ni] = *(const bf16x8*)(base + 8192 + byt);
      bu[ni] = *(const bf16x8*)(base + 16384 + byt);
    }
#pragma unroll
    for (int mi = 0; mi < 4; mi++)
#pragma unroll
      for (int ni = 0; ni < 4; ni++) {
        accg[mi][ni] = __builtin_amdgcn_mfma_f32_16x16x32_bf16(af[mi], bg[ni], accg[mi][ni], 0, 0, 0);
        accu[mi][ni] = __builtin_amdgcn_mfma_f32_16x16x32_bf16(af[mi], bu[ni], accu[mi][ni], 0, 0, 0);
      }
  };

  stage(0, 0);
  const int NKS = HD / 32;
  int ks = 0;
  for (; ks < NKS - 1; ks++) {
    stage((ks + 1) & 1, ks + 1);
    S_WAITCNT_VMCNT(6);      // wait for tile ks only; next tile stays in flight
    wave_barrier();
    compute(ks & 1);
    wave_barrier();
  }
  S_WAITCNT_VMCNT(0);
  wave_barrier();
  compute(ks & 1);

  const int rh = lane >> 4;
#pragma unroll
  for (int mi = 0; mi < 4; mi++)
#pragma unroll
    for (int ni = 0; ni < 4; ni++)
#pragma unroll
      for (int j = 0; j < 4; j++) {
        int grow = rowbase + wr * 64 + mi * 16 + rh * 4 + j;
        if (grow < rowend) {
          int gcol = i0 + wc * 64 + ni * 16 + rl;
          float g = accg[mi][ni][j], u = accu[mi][ni][j];
          float val = g / (1.f + __expf(-g)) * u;
          act[(size_t)grow * NI + gcol] = f2bf(val);
        }
      }
}

// ---------------- grouped GEMM 2: y[row] = act[row] @ Wd  (no atomics) ------
__launch_bounds__(256, 3)
__global__ void gemm2_kernel(const unsigned short* __restrict__ act,
                             const unsigned short* __restrict__ Wdt,
                             unsigned short* __restrict__ y,
                             const int* __restrict__ cnt) {
  const int f = blockIdx.x + 16 * (blockIdx.y + 32 * blockIdx.z);
  const int e = f & 7;
  const int rem = f >> 3;          // 0..511
  const int nt = rem >> 5;         // 0..15
  const int mt = rem & 31;         // 0..31
  const int c = cnt[e];
  if (mt * 128 >= c) return;
  const int off = cnt[8 + e];
  const int rowbase = off + mt * 128, rowend = off + c;
  const int n0 = nt * 128;
  __shared__ __align__(16) char smem[32768];
  const int lane = threadIdx.x & 63, w = threadIdx.x >> 6;
  const int wr = w >> 1, wc = w & 1;

  const int rr0 = w * 16 + (lane >> 2);
  const int rr1 = rr0 + 64;
  const int q0 = (lane & 3) ^ ((rr0 >> 1) & 3);
  const int q1 = (lane & 3) ^ ((rr1 >> 1) & 3);
  int g0 = rowbase + rr0; if (g0 > rowend - 1) g0 = rowend - 1;
  int g1 = rowbase + rr1; if (g1 > rowend - 1) g1 = rowend - 1;
  const size_t aA0 = (size_t)g0 * NI;
  const size_t aA1 = (size_t)g1 * NI;
  const size_t bB0 = ((size_t)e * HD + n0 + rr0) * NI;
  const size_t bB1 = ((size_t)e * HD + n0 + rr1) * NI;
  const int ldsA = w * 1024;

  f32x4 zero = {0.f, 0.f, 0.f, 0.f};
  f32x4 acc[4][4];
#pragma unroll
  for (int a = 0; a < 4; a++)
#pragma unroll
    for (int b = 0; b < 4; b++) acc[a][b] = zero;

  auto stage = [&](int buf, int ks) {
    const int k0 = ks * 32;
    char* base = smem + buf * 16384;
    gload_lds16(act + aA0 + k0 + q0 * 8, base + ldsA);
    gload_lds16(act + aA1 + k0 + q1 * 8, base + ldsA + 4096);
    gload_lds16(Wdt + bB0 + k0 + q0 * 8, base + 8192 + ldsA);
    gload_lds16(Wdt + bB1 + k0 + q1 * 8, base + 8192 + ldsA + 4096);
  };
  const int rl = lane & 15, kslot = lane >> 4;
  auto compute = [&](int buf) {
    const char* base = smem + buf * 16384;
    bf16x8 af[4], bf[4];
#pragma unroll
    for (int mi = 0; mi < 4; mi++) {
      int r = wr * 64 + mi * 16 + rl;
      int byt = r * 64 + ((kslot ^ ((r >> 1) & 3)) << 4);
      af[mi] = *(const bf16x8*)(base + byt);
    }
#pragma unroll
    for (int ni = 0; ni < 4; ni++) {
      int r = wc * 64 + ni * 16 + rl;
      int byt = r * 64 + ((kslot ^ ((r >> 1) & 3)) << 4);
      bf[ni] = *(const bf16x8*)(base + 8192 + byt);
    }
#pragma unroll
    for (int mi = 0; mi < 4; mi++)
#pragma unroll
      for (int ni = 0; ni < 4; ni++)
        acc[mi][ni] = __builtin_amdgcn_mfma_f32_16x16x32_bf16(af[mi], bf[ni], acc[mi][ni], 0, 0, 0);
  };

  stage(0, 0);
  const int NKS = NI / 32;
  int ks = 0;
  for (; ks < NKS - 1; ks++) {
    stage((ks + 1) & 1, ks + 1);
    S_WAITCNT_VMCNT(4);
    wave_barrier();
    compute(ks & 1);
    wave_barrier();
  }
  S_WAITCNT_VMCNT(0);
  wave_barrier();
  compute(ks & 1);

  const int rh = lane >> 4;
#pragma unroll
  for (int mi = 0; mi < 4; mi++)
#pragma unroll
    for (int ni = 0; ni < 4; ni++)
#pragma unroll
      for (int j = 0; j < 4; j++) {
        int grow = rowbase + wr * 64 + mi * 16 + rh * 4 + j;
        if (grow < rowend) {
          int gcol = n0 + wc * 64 + ni * 16 + rl;
          y[(size_t)grow * HD + gcol] = f2bf(acc[mi][ni][j]);
        }
      }
}

// ---------------- combine: out[t] = w0*y[r0] + w1*y[r1] ----------------
__global__ void combine_kernel(const unsigned short* __restrict__ y,
                               const int2* __restrict__ tok2row,
                               const int4* __restrict__ tokinfo,
                               float* __restrict__ out) {
  int t = blockIdx.x, tid = threadIdx.x;
  int2 rr = tok2row[t];
  int4 info = tokinfo[t];
  float w0 = __int_as_float(info.z), w1 = __int_as_float(info.w);
  ushort8 a = ((const ushort8*)(y + (size_t)rr.x * HD))[tid];
  ushort8 b = ((const ushort8*)(y + (size_t)rr.y * HD))[tid];
  float4 o0, o1;
  o0.x = w0 * bf2f(a[0]) + w1 * bf2f(b[0]);
  o0.y = w0 * bf2f(a[1]) + w1 * bf2f(b[1]);
  o0.z = w0 * bf2f(a[2]) + w1 * bf2f(b[2]);
  o0.w = w0 * bf2f(a[3]) + w1 * bf2f(b[3]);
  o1.x = w0 * bf2f(a[4]) + w1 * bf2f(b[4]);
  o1.y = w0 * bf2f(a[5]) + w1 * bf2f(b[5]);
  o1.z = w0 * bf2f(a[6]) + w1 * bf2f(b[6]);
  o1.w = w0 * bf2f(a[7]) + w1 * bf2f(b[7]);
  float4* op = (float4*)(out + (size_t)t * HD + tid * 8);
  op[0] = o0; op[1] = o1;
}

// ---------------- launch ----------------
extern "C" void kernel_launch(void* const* d_in, const int* in_sizes, int n_in,
                              void* d_out, int out_size, void* d_ws, size_t ws_size,
                              hipStream_t stream) {
  const float* x  = (const float*)d_in[0];
  const float* Wr = (const float*)d_in[1];
  const float* Wg = (const float*)d_in[2];
  const float* Wu = (const float*)d_in[3];
  const float* Wd = (const float*)d_in[4];
  float* out = (float*)d_out;
  char* ws = (char*)d_ws;

  // ws layout (bytes)
  unsigned short* xbf = (unsigned short*)(ws);                 // 16,777,216
  unsigned short* Wgt = (unsigned short*)(ws + 16777216);      // 46,137,344
  unsigned short* Wut = (unsigned short*)(ws + 62914560);      // 46,137,344
  unsigned short* Wdt = (unsigned short*)(ws + 109051904);     // 46,137,344
  unsigned short* act = (unsigned short*)(ws + 155189248);     // 23,068,672
  // y aliases Wgt: gemm1 (last reader of Wgt) completes before gemm2 writes y.
  unsigned short* yb  = (unsigned short*)(ws + 16777216);      // 33,554,432
  int4*  tokinfo      = (int4*)(ws + 178257920);               // 65,536
  int*   row_tok      = (int*)(ws + 178323456);                // 32,768
  int2*  tok2row      = (int2*)(ws + 178356224);               // 32,768
  int*   cnt          = (int*)(ws + 178388992);                // 128

  hipMemsetAsync(cnt, 0, 128, stream);

  router_kernel<<<T_TOK / 4, 256, 0, stream>>>(x, Wr, out + (size_t)T_TOK * HD, xbf, tokinfo, cnt);
  offsets_kernel<<<1, 1, 0, stream>>>(cnt);
  scatter_kernel<<<T_TOK / 256, 256, 0, stream>>>(tokinfo, cnt, row_tok, tok2row);

  // Wg+Wu in one launch (dual), Wd separate.  128-row x 64-col tiles.
  transpose_cvt2_kernel<<<dim3(NI / 64, HD / 128, NE * 2), 256, 0, stream>>>(
      Wg, Wgt, Wu, Wut, HD, NI, 1);
  transpose_cvt2_kernel<<<dim3(HD / 64, NI / 128, NE), 256, 0, stream>>>(
      Wd, Wdt, nullptr, nullptr, NI, HD, 0);

  gemm1_kernel<<<dim3(11, 32, NE), 256, 0, stream>>>(xbf, Wgt, Wut, act, row_tok, cnt);
  gemm2_kernel<<<dim3(16, 32, NE), 256, 0, stream>>>(act, Wdt, yb, cnt);
  combine_kernel<<<T_TOK, 256, 0, stream>>>(yb, tok2row, tokinfo, out);
}

// Round 9
// 462.045 us; speedup vs baseline: 1.2886x; 1.0233x over previous
//
#include <hip/hip_runtime.h>

#define T_TOK 4096
#define HD 2048
#define NE 8
#define NI 1408

typedef __bf16 bf16x8 __attribute__((ext_vector_type(8)));
typedef float f32x4 __attribute__((ext_vector_type(4)));
typedef unsigned short ushort8 __attribute__((ext_vector_type(8)));

#define S_WAITCNT_VMCNT(n) asm volatile("s_waitcnt vmcnt(" #n ")" ::: "memory")
__device__ __forceinline__ void wave_barrier() {
  asm volatile("" ::: "memory");
  __builtin_amdgcn_s_barrier();
  asm volatile("" ::: "memory");
}

__device__ __forceinline__ unsigned short f2bf(float f) {
  unsigned int u = __float_as_uint(f);
  u += 0x7FFFu + ((u >> 16) & 1u);
  return (unsigned short)(u >> 16);
}
__device__ __forceinline__ float bf2f(unsigned short u) {
  return __uint_as_float((unsigned int)u << 16);
}

__device__ __forceinline__ void gload_lds16(const void* g, void* l) {
  __builtin_amdgcn_global_load_lds(
      (const __attribute__((address_space(1))) unsigned int*)g,
      (__attribute__((address_space(3))) unsigned int*)l, 16, 0, 0);
}

// src [E][R][C] f32 -> dst [E][C][R] bf16.  128(r) x 64(c) tile, 256 threads,
// register-only 8x4 transpose per thread, NO LDS.
// dual=1: blockIdx.z&1 selects (srcA,dstA)/(srcB,dstB).
__global__ void transpose_cvt2_kernel(const float* __restrict__ srcA,
                                      unsigned short* __restrict__ dstA,
                                      const float* __restrict__ srcB,
                                      unsigned short* __restrict__ dstB,
                                      int R, int C, int dual) {
  int z = blockIdx.z;
  int e = dual ? (z >> 1) : z;
  const float* sp = (dual && (z & 1)) ? srcB : srcA;
  unsigned short* dp = (dual && (z & 1)) ? dstB : dstA;
  int c0 = blockIdx.x * 64, r0 = blockIdx.y * 128;
  const float* s = sp + (size_t)e * R * C;
  unsigned short* d = dp + (size_t)e * R * C;
  int tid = threadIdx.x;
  int tj = tid & 15, ti = tid >> 4;
  const float* sb = s + (size_t)(r0 + ti * 8) * C + c0 + tj * 4;
  f32x4 v[8];
#pragma unroll
  for (int r = 0; r < 8; r++) v[r] = *(const f32x4*)(sb + (size_t)r * C);
  unsigned short* db = d + (size_t)(c0 + tj * 4) * R + r0 + ti * 8;
#pragma unroll
  for (int cc = 0; cc < 4; cc++) {
    ushort8 o;
#pragma unroll
    for (int r = 0; r < 8; r++) o[r] = f2bf(v[r][cc]);
    *(ushort8*)(db + (size_t)cc * R) = o;
  }
}

// ---------------- routing (also emits x in bf16), float4-vectorized --------
__global__ void router_kernel(const float* __restrict__ x,
                              const float* __restrict__ Wr,
                              float* __restrict__ logits,
                              unsigned short* __restrict__ xbf,
                              int4* __restrict__ tokinfo,
                              int* __restrict__ cnt) {
  int wv = threadIdx.x >> 6, lane = threadIdx.x & 63;
  int t = blockIdx.x * 4 + wv;
  const float* xr = x + (size_t)t * HD;
  unsigned short* xbr = xbf + (size_t)t * HD;
  float acc[NE];
#pragma unroll
  for (int e = 0; e < NE; e++) acc[e] = 0.f;
  for (int hi = 0; hi < HD / 256; hi++) {
    int h = hi * 256 + lane * 4;
    f32x4 xv = *(const f32x4*)(xr + h);
    ushort4 o = { f2bf(xv[0]), f2bf(xv[1]), f2bf(xv[2]), f2bf(xv[3]) };
    *(ushort4*)(xbr + h) = o;
#pragma unroll
    for (int j = 0; j < 4; j++) {
      const float4* w4 = (const float4*)(Wr + (size_t)(h + j) * NE);
      float4 a = w4[0], b = w4[1];
      float xs = xv[j];
      acc[0] += xs * a.x; acc[1] += xs * a.y; acc[2] += xs * a.z; acc[3] += xs * a.w;
      acc[4] += xs * b.x; acc[5] += xs * b.y; acc[6] += xs * b.z; acc[7] += xs * b.w;
    }
  }
#pragma unroll
  for (int m = 32; m > 0; m >>= 1) {
#pragma unroll
    for (int e = 0; e < NE; e++) acc[e] += __shfl_xor(acc[e], m, 64);
  }
  if (lane < NE) logits[(size_t)t * NE + lane] = acc[lane];
  if (lane == 0) {
    int e0 = 0;
#pragma unroll
    for (int e = 1; e < NE; e++) if (acc[e] > acc[e0]) e0 = e;
    int e1 = (e0 == 0) ? 1 : 0;
#pragma unroll
    for (int e = 0; e < NE; e++) if (e != e0 && acc[e] > acc[e1]) e1 = e;
    float ex = expf(acc[e1] - acc[e0]);   // <= 1
    float w0 = 1.f / (1.f + ex);
    float w1 = ex / (1.f + ex);
    atomicAdd(&cnt[e0], 1);
    atomicAdd(&cnt[e1], 1);
    tokinfo[t] = make_int4(e0, e1, __float_as_int(w0), __float_as_int(w1));
  }
}

// Fused offsets + scatter, single block (1024 threads).
// cnt[0..7]=counts, [8..15]=offsets, [16..23]=cursors.
__global__ void route_finalize_kernel(const int4* __restrict__ tokinfo,
                                      int* __restrict__ cnt,
                                      int* __restrict__ row_tok,
                                      int2* __restrict__ tok2row) {
  if (threadIdx.x == 0) {
    int o = 0;
    for (int e = 0; e < NE; e++) { cnt[8 + e] = o; o += cnt[e]; }
  }
  __syncthreads();
  for (int t = threadIdx.x; t < T_TOK; t += 1024) {
    int4 info = tokinfo[t];
    int p0 = atomicAdd(&cnt[16 + info.x], 1);
    int r0 = cnt[8 + info.x] + p0;
    row_tok[r0] = t;
    int p1 = atomicAdd(&cnt[16 + info.y], 1);
    int r1 = cnt[8 + info.y] + p1;
    row_tok[r1] = t;
    tok2row[t] = make_int2(r0, r1);
  }
}

// ---------------- grouped GEMM 1: act = silu(x@Wg) * (x@Wu) ----------------
// 128x128 tile, BK=32, 4 waves, 16x16x32 MFMA, conflict-free XOR slots,
// static XCD swizzle expert = flat_id & 7 (R7: dynamic queue loses L2
// affinity). DEPTH-3 counted-vmcnt pipeline: stage tile ks+2, steady-state
// wait vmcnt(12) = 2 tiles in flight, gives loads 2 compute-phases to cover
// L2/L3 latency. LDS 3 x 24KB = 72KB, 2 blocks/CU = 144KB <= 160.
// launch_bounds MUST stay (256,2): 128 acc + ~100 VGPR (R2 spill lesson).
__launch_bounds__(256, 2)
__global__ void gemm1_kernel(const unsigned short* __restrict__ xbf,
                             const unsigned short* __restrict__ Wgt,
                             const unsigned short* __restrict__ Wut,
                             unsigned short* __restrict__ act,
                             const int* __restrict__ row_tok,
                             const int* __restrict__ cnt) {
  const int f = blockIdx.x + 11 * (blockIdx.y + 32 * blockIdx.z);
  const int e = f & 7;
  const int rem = f >> 3;          // 0..351
  const int nt = rem >> 5;         // 0..10
  const int mt = rem & 31;         // 0..31
  const int c = cnt[e];
  if (mt * 128 >= c) return;
  const int off = cnt[8 + e];
  const int rowbase = off + mt * 128, rowend = off + c;
  const int i0 = nt * 128;
  __shared__ __align__(16) char smem[73728];
  const int lane = threadIdx.x & 63, w = threadIdx.x >> 6;
  const int wr = w >> 1, wc = w & 1;

  const int rr0 = w * 16 + (lane >> 2);
  const int rr1 = rr0 + 64;
  const int q0 = (lane & 3) ^ ((rr0 >> 1) & 3);
  const int q1 = (lane & 3) ^ ((rr1 >> 1) & 3);
  int g0 = rowbase + rr0; if (g0 > rowend - 1) g0 = rowend - 1;
  int g1 = rowbase + rr1; if (g1 > rowend - 1) g1 = rowend - 1;
  const size_t tokA0 = (size_t)row_tok[g0] * HD;
  const size_t tokA1 = (size_t)row_tok[g1] * HD;
  const size_t bB0 = ((size_t)e * NI + i0 + rr0) * HD;
  const size_t bB1 = ((size_t)e * NI + i0 + rr1) * HD;
  const int ldsA = w * 1024;

  f32x4 zero = {0.f, 0.f, 0.f, 0.f};
  f32x4 accg[4][4], accu[4][4];
#pragma unroll
  for (int a = 0; a < 4; a++)
#pragma unroll
    for (int b = 0; b < 4; b++) { accg[a][b] = zero; accu[a][b] = zero; }

  auto stage = [&](int buf, int ks) {
    const int k0 = ks * 32;
    char* base = smem + buf * 24576;
    gload_lds16(xbf + tokA0 + k0 + q0 * 8, base + ldsA);
    gload_lds16(xbf + tokA1 + k0 + q1 * 8, base + ldsA + 4096);
    gload_lds16(Wgt + bB0 + k0 + q0 * 8, base + 8192 + ldsA);
    gload_lds16(Wgt + bB1 + k0 + q1 * 8, base + 8192 + ldsA + 4096);
    gload_lds16(Wut + bB0 + k0 + q0 * 8, base + 16384 + ldsA);
    gload_lds16(Wut + bB1 + k0 + q1 * 8, base + 16384 + ldsA + 4096);
  };
  const int rl = lane & 15, kslot = lane >> 4;
  auto compute = [&](int buf) {
    const char* base = smem + buf * 24576;
    bf16x8 af[4], bg[4], bu[4];
#pragma unroll
    for (int mi = 0; mi < 4; mi++) {
      int r = wr * 64 + mi * 16 + rl;
      int byt = r * 64 + ((kslot ^ ((r >> 1) & 3)) << 4);
      af[mi] = *(const bf16x8*)(base + byt);
    }
#pragma unroll
    for (int ni = 0; ni < 4; ni++) {
      int r = wc * 64 + ni * 16 + rl;
      int byt = r * 64 + ((kslot ^ ((r >> 1) & 3)) << 4);
      bg[ni] = *(const bf16x8*)(base + 8192 + byt);
      bu[ni] = *(const bf16x8*)(base + 16384 + byt);
    }
#pragma unroll
    for (int mi = 0; mi < 4; mi++)
#pragma unroll
      for (int ni = 0; ni < 4; ni++) {
        accg[mi][ni] = __builtin_amdgcn_mfma_f32_16x16x32_bf16(af[mi], bg[ni], accg[mi][ni], 0, 0, 0);
        accu[mi][ni] = __builtin_amdgcn_mfma_f32_16x16x32_bf16(af[mi], bu[ni], accu[mi][ni], 0, 0, 0);
      }
  };

  stage(0, 0);
  stage(1, 1);
  const int NKS = HD / 32;
  for (int ks = 0; ks < NKS; ks++) {
    if (ks + 2 < NKS) {
      stage((ks + 2) % 3, ks + 2);
      S_WAITCNT_VMCNT(12);   // tile ks complete; ks+1, ks+2 in flight
    } else if (ks + 1 < NKS) {
      S_WAITCNT_VMCNT(6);    // tile ks complete; ks+1 in flight
    } else {
      S_WAITCNT_VMCNT(0);
    }
    wave_barrier();
    compute(ks % 3);
    wave_barrier();
  }

  const int rh = lane >> 4;
#pragma unroll
  for (int mi = 0; mi < 4; mi++)
#pragma unroll
    for (int ni = 0; ni < 4; ni++)
#pragma unroll
      for (int j = 0; j < 4; j++) {
        int grow = rowbase + wr * 64 + mi * 16 + rh * 4 + j;
        if (grow < rowend) {
          int gcol = i0 + wc * 64 + ni * 16 + rl;
          float g = accg[mi][ni][j], u = accu[mi][ni][j];
          float val = g / (1.f + __expf(-g)) * u;
          act[(size_t)grow * NI + gcol] = f2bf(val);
        }
      }
}

// ---------------- grouped GEMM 2: y[row] = act[row] @ Wd  (no atomics) ------
// DEPTH-3 pipeline: LDS 3 x 16KB = 48KB, 3 blocks/CU = 144KB <= 160.
__launch_bounds__(256, 3)
__global__ void gemm2_kernel(const unsigned short* __restrict__ act,
                             const unsigned short* __restrict__ Wdt,
                             unsigned short* __restrict__ y,
                             const int* __restrict__ cnt) {
  const int f = blockIdx.x + 16 * (blockIdx.y + 32 * blockIdx.z);
  const int e = f & 7;
  const int rem = f >> 3;          // 0..511
  const int nt = rem >> 5;         // 0..15
  const int mt = rem & 31;         // 0..31
  const int c = cnt[e];
  if (mt * 128 >= c) return;
  const int off = cnt[8 + e];
  const int rowbase = off + mt * 128, rowend = off + c;
  const int n0 = nt * 128;
  __shared__ __align__(16) char smem[49152];
  const int lane = threadIdx.x & 63, w = threadIdx.x >> 6;
  const int wr = w >> 1, wc = w & 1;

  const int rr0 = w * 16 + (lane >> 2);
  const int rr1 = rr0 + 64;
  const int q0 = (lane & 3) ^ ((rr0 >> 1) & 3);
  const int q1 = (lane & 3) ^ ((rr1 >> 1) & 3);
  int g0 = rowbase + rr0; if (g0 > rowend - 1) g0 = rowend - 1;
  int g1 = rowbase + rr1; if (g1 > rowend - 1) g1 = rowend - 1;
  const size_t aA0 = (size_t)g0 * NI;
  const size_t aA1 = (size_t)g1 * NI;
  const size_t bB0 = ((size_t)e * HD + n0 + rr0) * NI;
  const size_t bB1 = ((size_t)e * HD + n0 + rr1) * NI;
  const int ldsA = w * 1024;

  f32x4 zero = {0.f, 0.f, 0.f, 0.f};
  f32x4 acc[4][4];
#pragma unroll
  for (int a = 0; a < 4; a++)
#pragma unroll
    for (int b = 0; b < 4; b++) acc[a][b] = zero;

  auto stage = [&](int buf, int ks) {
    const int k0 = ks * 32;
    char* base = smem + buf * 16384;
    gload_lds16(act + aA0 + k0 + q0 * 8, base + ldsA);
    gload_lds16(act + aA1 + k0 + q1 * 8, base + ldsA + 4096);
    gload_lds16(Wdt + bB0 + k0 + q0 * 8, base + 8192 + ldsA);
    gload_lds16(Wdt + bB1 + k0 + q1 * 8, base + 8192 + ldsA + 4096);
  };
  const int rl = lane & 15, kslot = lane >> 4;
  auto compute = [&](int buf) {
    const char* base = smem + buf * 16384;
    bf16x8 af[4], bf[4];
#pragma unroll
    for (int mi = 0; mi < 4; mi++) {
      int r = wr * 64 + mi * 16 + rl;
      int byt = r * 64 + ((kslot ^ ((r >> 1) & 3)) << 4);
      af[mi] = *(const bf16x8*)(base + byt);
    }
#pragma unroll
    for (int ni = 0; ni < 4; ni++) {
      int r = wc * 64 + ni * 16 + rl;
      int byt = r * 64 + ((kslot ^ ((r >> 1) & 3)) << 4);
      bf[ni] = *(const bf16x8*)(base + 8192 + byt);
    }
#pragma unroll
    for (int mi = 0; mi < 4; mi++)
#pragma unroll
      for (int ni = 0; ni < 4; ni++)
        acc[mi][ni] = __builtin_amdgcn_mfma_f32_16x16x32_bf16(af[mi], bf[ni], acc[mi][ni], 0, 0, 0);
  };

  stage(0, 0);
  stage(1, 1);
  const int NKS = NI / 32;
  for (int ks = 0; ks < NKS; ks++) {
    if (ks + 2 < NKS) {
      stage((ks + 2) % 3, ks + 2);
      S_WAITCNT_VMCNT(8);
    } else if (ks + 1 < NKS) {
      S_WAITCNT_VMCNT(4);
    } else {
      S_WAITCNT_VMCNT(0);
    }
    wave_barrier();
    compute(ks % 3);
    wave_barrier();
  }

  const int rh = lane >> 4;
#pragma unroll
  for (int mi = 0; mi < 4; mi++)
#pragma unroll
    for (int ni = 0; ni < 4; ni++)
#pragma unroll
      for (int j = 0; j < 4; j++) {
        int grow = rowbase + wr * 64 + mi * 16 + rh * 4 + j;
        if (grow < rowend) {
          int gcol = n0 + wc * 64 + ni * 16 + rl;
          y[(size_t)grow * HD + gcol] = f2bf(acc[mi][ni][j]);
        }
      }
}

// ---------------- combine: out[t] = w0*y[r0] + w1*y[r1] ----------------
__global__ void combine_kernel(const unsigned short* __restrict__ y,
                               const int2* __restrict__ tok2row,
                               const int4* __restrict__ tokinfo,
                               float* __restrict__ out) {
  int t = blockIdx.x, tid = threadIdx.x;
  int2 rr = tok2row[t];
  int4 info = tokinfo[t];
  float w0 = __int_as_float(info.z), w1 = __int_as_float(info.w);
  ushort8 a = ((const ushort8*)(y + (size_t)rr.x * HD))[tid];
  ushort8 b = ((const ushort8*)(y + (size_t)rr.y * HD))[tid];
  float4 o0, o1;
  o0.x = w0 * bf2f(a[0]) + w1 * bf2f(b[0]);
  o0.y = w0 * bf2f(a[1]) + w1 * bf2f(b[1]);
  o0.z = w0 * bf2f(a[2]) + w1 * bf2f(b[2]);
  o0.w = w0 * bf2f(a[3]) + w1 * bf2f(b[3]);
  o1.x = w0 * bf2f(a[4]) + w1 * bf2f(b[4]);
  o1.y = w0 * bf2f(a[5]) + w1 * bf2f(b[5]);
  o1.z = w0 * bf2f(a[6]) + w1 * bf2f(b[6]);
  o1.w = w0 * bf2f(a[7]) + w1 * bf2f(b[7]);
  float4* op = (float4*)(out + (size_t)t * HD + tid * 8);
  op[0] = o0; op[1] = o1;
}

// ---------------- launch ----------------
extern "C" void kernel_launch(void* const* d_in, const int* in_sizes, int n_in,
                              void* d_out, int out_size, void* d_ws, size_t ws_size,
                              hipStream_t stream) {
  const float* x  = (const float*)d_in[0];
  const float* Wr = (const float*)d_in[1];
  const float* Wg = (const float*)d_in[2];
  const float* Wu = (const float*)d_in[3];
  const float* Wd = (const float*)d_in[4];
  float* out = (float*)d_out;
  char* ws = (char*)d_ws;

  // ws layout (bytes)
  unsigned short* xbf = (unsigned short*)(ws);                 // 16,777,216
  unsigned short* Wgt = (unsigned short*)(ws + 16777216);      // 46,137,344
  unsigned short* Wut = (unsigned short*)(ws + 62914560);      // 46,137,344
  unsigned short* Wdt = (unsigned short*)(ws + 109051904);     // 46,137,344
  unsigned short* act = (unsigned short*)(ws + 155189248);     // 23,068,672
  // y aliases Wgt: gemm1 (last reader of Wgt) completes before gemm2 writes y.
  unsigned short* yb  = (unsigned short*)(ws + 16777216);      // 33,554,432
  int4*  tokinfo      = (int4*)(ws + 178257920);               // 65,536
  int*   row_tok      = (int*)(ws + 178323456);                // 32,768
  int2*  tok2row      = (int2*)(ws + 178356224);               // 32,768
  int*   cnt          = (int*)(ws + 178388992);                // 128

  hipMemsetAsync(cnt, 0, 128, stream);

  router_kernel<<<T_TOK / 4, 256, 0, stream>>>(x, Wr, out + (size_t)T_TOK * HD, xbf, tokinfo, cnt);
  route_finalize_kernel<<<1, 1024, 0, stream>>>(tokinfo, cnt, row_tok, tok2row);

  // Wg+Wu in one launch (dual), Wd separate.  128-row x 64-col tiles.
  transpose_cvt2_kernel<<<dim3(NI / 64, HD / 128, NE * 2), 256, 0, stream>>>(
      Wg, Wgt, Wu, Wut, HD, NI, 1);
  transpose_cvt2_kernel<<<dim3(HD / 64, NI / 128, NE), 256, 0, stream>>>(
      Wd, Wdt, nullptr, nullptr, NI, HD, 0);

  gemm1_kernel<<<dim3(11, 32, NE), 256, 0, stream>>>(xbf, Wgt, Wut, act, row_tok, cnt);
  gemm2_kernel<<<dim3(16, 32, NE), 256, 0, stream>>>(act, Wdt, yb, cnt);
  combine_kernel<<<T_TOK, 256, 0, stream>>>(yb, tok2row, tokinfo, out);
}

// Round 10
// 441.546 us; speedup vs baseline: 1.3484x; 1.0464x over previous
//
#include <hip/hip_runtime.h>

#define T_TOK 4096
#define HD 2048
#define NE 8
#define NI 1408

typedef __bf16 bf16x8 __attribute__((ext_vector_type(8)));
typedef float f32x4 __attribute__((ext_vector_type(4)));
typedef unsigned short ushort8 __attribute__((ext_vector_type(8)));

#define S_WAITCNT_VMCNT(n) asm volatile("s_waitcnt vmcnt(" #n ")" ::: "memory")
__device__ __forceinline__ void wave_barrier() {
  asm volatile("" ::: "memory");
  __builtin_amdgcn_s_barrier();
  asm volatile("" ::: "memory");
}

__device__ __forceinline__ unsigned short f2bf(float f) {
  unsigned int u = __float_as_uint(f);
  u += 0x7FFFu + ((u >> 16) & 1u);
  return (unsigned short)(u >> 16);
}
__device__ __forceinline__ float bf2f(unsigned short u) {
  return __uint_as_float((unsigned int)u << 16);
}

__device__ __forceinline__ void gload_lds16(const void* g, void* l) {
  __builtin_amdgcn_global_load_lds(
      (const __attribute__((address_space(1))) unsigned int*)g,
      (__attribute__((address_space(3))) unsigned int*)l, 16, 0, 0);
}

// ---------------- fused prepass: router + Wg/Wu transpose + Wd transpose ----
// All three are independent; one launch overlaps them.
// bid < 1024                : router block (4 tokens each)
// 1024 <= bid < 1024+5632   : Wg/Wu transpose (22 x 16 x 16)
// else (2816 blocks)        : Wd transpose   (32 x 11 x 8)
__device__ __forceinline__ void transpose_body(const float* s,
                                               unsigned short* d,
                                               int R, int C, int r0, int c0) {
  int tid = threadIdx.x;
  int tj = tid & 15, ti = tid >> 4;
  const float* sb = s + (size_t)(r0 + ti * 8) * C + c0 + tj * 4;
  f32x4 v[8];
#pragma unroll
  for (int r = 0; r < 8; r++) v[r] = *(const f32x4*)(sb + (size_t)r * C);
  unsigned short* db = d + (size_t)(c0 + tj * 4) * R + r0 + ti * 8;
#pragma unroll
  for (int cc = 0; cc < 4; cc++) {
    ushort8 o;
#pragma unroll
    for (int r = 0; r < 8; r++) o[r] = f2bf(v[r][cc]);
    *(ushort8*)(db + (size_t)cc * R) = o;
  }
}

__global__ void prepass_kernel(const float* __restrict__ x,
                               const float* __restrict__ Wr,
                               const float* __restrict__ Wg,
                               const float* __restrict__ Wu,
                               const float* __restrict__ Wd,
                               float* __restrict__ logits,
                               unsigned short* __restrict__ xbf,
                               unsigned short* __restrict__ Wgt,
                               unsigned short* __restrict__ Wut,
                               unsigned short* __restrict__ Wdt,
                               int4* __restrict__ tokinfo,
                               int* __restrict__ cnt) {
  const int bid = blockIdx.x;
  if (bid < 1024) {
    // -------- router: 4 tokens per block, wave per token --------
    int wv = threadIdx.x >> 6, lane = threadIdx.x & 63;
    int t = bid * 4 + wv;
    const float* xr = x + (size_t)t * HD;
    unsigned short* xbr = xbf + (size_t)t * HD;
    float acc[NE];
#pragma unroll
    for (int e = 0; e < NE; e++) acc[e] = 0.f;
    for (int hi = 0; hi < HD / 256; hi++) {
      int h = hi * 256 + lane * 4;
      f32x4 xv = *(const f32x4*)(xr + h);
      ushort4 o = { f2bf(xv[0]), f2bf(xv[1]), f2bf(xv[2]), f2bf(xv[3]) };
      *(ushort4*)(xbr + h) = o;
#pragma unroll
      for (int j = 0; j < 4; j++) {
        const float4* w4 = (const float4*)(Wr + (size_t)(h + j) * NE);
        float4 a = w4[0], b = w4[1];
        float xs = xv[j];
        acc[0] += xs * a.x; acc[1] += xs * a.y; acc[2] += xs * a.z; acc[3] += xs * a.w;
        acc[4] += xs * b.x; acc[5] += xs * b.y; acc[6] += xs * b.z; acc[7] += xs * b.w;
      }
    }
#pragma unroll
    for (int m = 32; m > 0; m >>= 1) {
#pragma unroll
      for (int e = 0; e < NE; e++) acc[e] += __shfl_xor(acc[e], m, 64);
    }
    if (lane < NE) logits[(size_t)t * NE + lane] = acc[lane];
    if (lane == 0) {
      int e0 = 0;
#pragma unroll
      for (int e = 1; e < NE; e++) if (acc[e] > acc[e0]) e0 = e;
      int e1 = (e0 == 0) ? 1 : 0;
#pragma unroll
      for (int e = 0; e < NE; e++) if (e != e0 && acc[e] > acc[e1]) e1 = e;
      float ex = expf(acc[e1] - acc[e0]);   // <= 1
      float w0 = 1.f / (1.f + ex);
      float w1 = ex / (1.f + ex);
      atomicAdd(&cnt[e0], 1);
      atomicAdd(&cnt[e1], 1);
      tokinfo[t] = make_int4(e0, e1, __float_as_int(w0), __float_as_int(w1));
    }
  } else if (bid < 1024 + 5632) {
    // -------- Wg/Wu transpose: [E][HD][NI] -> [E][NI][HD] --------
    int r = bid - 1024;
    int xt = r % 22; r /= 22;
    int yt = r % 16; r /= 16;
    int e = r >> 1, sel = r & 1;
    const float* sp = (sel ? Wu : Wg) + (size_t)e * HD * NI;
    unsigned short* dp = (sel ? Wut : Wgt) + (size_t)e * HD * NI;
    transpose_body(sp, dp, HD, NI, yt * 128, xt * 64);
  } else {
    // -------- Wd transpose: [E][NI][HD] -> [E][HD][NI] --------
    int r = bid - 1024 - 5632;
    int xt = r % 32; r /= 32;
    int yt = r % 11; r /= 11;
    int e = r;
    const float* sp = Wd + (size_t)e * NI * HD;
    unsigned short* dp = Wdt + (size_t)e * NI * HD;
    transpose_body(sp, dp, NI, HD, yt * 128, xt * 64);
  }
}

// Fused offsets + scatter, single block (1024 threads).
// cnt[0..7]=counts, [8..15]=offsets, [16..23]=cursors.
__global__ void route_finalize_kernel(const int4* __restrict__ tokinfo,
                                      int* __restrict__ cnt,
                                      int* __restrict__ row_tok,
                                      int2* __restrict__ tok2row) {
  if (threadIdx.x == 0) {
    int o = 0;
    for (int e = 0; e < NE; e++) { cnt[8 + e] = o; o += cnt[e]; }
  }
  __syncthreads();
  for (int t = threadIdx.x; t < T_TOK; t += 1024) {
    int4 info = tokinfo[t];
    int p0 = atomicAdd(&cnt[16 + info.x], 1);
    int r0 = cnt[8 + info.x] + p0;
    row_tok[r0] = t;
    int p1 = atomicAdd(&cnt[16 + info.y], 1);
    int r1 = cnt[8 + info.y] + p1;
    row_tok[r1] = t;
    tok2row[t] = make_int2(r0, r1);
  }
}

// ---------------- grouped GEMM 1: act = silu(x@Wg) * (x@Wu) ----------------
// 128x128 tile, BK=32, 4 waves, 16x16x32 MFMA, conflict-free XOR slots,
// static XCD swizzle expert = flat_id & 7.  ONE barrier per K-step (T3):
// depth-3 buffers allow {vmcnt(6); barrier; stage(ks+2); compute(ks)} —
// the top barrier proves all waves finished compute(ks-1), so stage(ks+2)
// (-> buf (ks-1)%3) is race-free, and DMA issue overlaps the whole compute.
// launch_bounds MUST stay (256,2): 128 acc + ~100 VGPR (R2 spill lesson).
__launch_bounds__(256, 2)
__global__ void gemm1_kernel(const unsigned short* __restrict__ xbf,
                             const unsigned short* __restrict__ Wgt,
                             const unsigned short* __restrict__ Wut,
                             unsigned short* __restrict__ act,
                             const int* __restrict__ row_tok,
                             const int* __restrict__ cnt) {
  const int f = blockIdx.x + 11 * (blockIdx.y + 32 * blockIdx.z);
  const int e = f & 7;
  const int rem = f >> 3;          // 0..351
  const int nt = rem >> 5;         // 0..10
  const int mt = rem & 31;         // 0..31
  const int c = cnt[e];
  if (mt * 128 >= c) return;
  const int off = cnt[8 + e];
  const int rowbase = off + mt * 128, rowend = off + c;
  const int i0 = nt * 128;
  __shared__ __align__(16) char smem[73728];
  const int lane = threadIdx.x & 63, w = threadIdx.x >> 6;
  const int wr = w >> 1, wc = w & 1;

  const int rr0 = w * 16 + (lane >> 2);
  const int rr1 = rr0 + 64;
  const int q0 = (lane & 3) ^ ((rr0 >> 1) & 3);
  const int q1 = (lane & 3) ^ ((rr1 >> 1) & 3);
  int g0 = rowbase + rr0; if (g0 > rowend - 1) g0 = rowend - 1;
  int g1 = rowbase + rr1; if (g1 > rowend - 1) g1 = rowend - 1;
  const size_t tokA0 = (size_t)row_tok[g0] * HD;
  const size_t tokA1 = (size_t)row_tok[g1] * HD;
  const size_t bB0 = ((size_t)e * NI + i0 + rr0) * HD;
  const size_t bB1 = ((size_t)e * NI + i0 + rr1) * HD;
  const int ldsA = w * 1024;

  f32x4 zero = {0.f, 0.f, 0.f, 0.f};
  f32x4 accg[4][4], accu[4][4];
#pragma unroll
  for (int a = 0; a < 4; a++)
#pragma unroll
    for (int b = 0; b < 4; b++) { accg[a][b] = zero; accu[a][b] = zero; }

  auto stage = [&](int buf, int ks) {
    const int k0 = ks * 32;
    char* base = smem + buf * 24576;
    gload_lds16(xbf + tokA0 + k0 + q0 * 8, base + ldsA);
    gload_lds16(xbf + tokA1 + k0 + q1 * 8, base + ldsA + 4096);
    gload_lds16(Wgt + bB0 + k0 + q0 * 8, base + 8192 + ldsA);
    gload_lds16(Wgt + bB1 + k0 + q1 * 8, base + 8192 + ldsA + 4096);
    gload_lds16(Wut + bB0 + k0 + q0 * 8, base + 16384 + ldsA);
    gload_lds16(Wut + bB1 + k0 + q1 * 8, base + 16384 + ldsA + 4096);
  };
  const int rl = lane & 15, kslot = lane >> 4;
  auto compute = [&](int buf) {
    const char* base = smem + buf * 24576;
    bf16x8 af[4], bg[4], bu[4];
#pragma unroll
    for (int mi = 0; mi < 4; mi++) {
      int r = wr * 64 + mi * 16 + rl;
      int byt = r * 64 + ((kslot ^ ((r >> 1) & 3)) << 4);
      af[mi] = *(const bf16x8*)(base + byt);
    }
#pragma unroll
    for (int ni = 0; ni < 4; ni++) {
      int r = wc * 64 + ni * 16 + rl;
      int byt = r * 64 + ((kslot ^ ((r >> 1) & 3)) << 4);
      bg[ni] = *(const bf16x8*)(base + 8192 + byt);
      bu[ni] = *(const bf16x8*)(base + 16384 + byt);
    }
#pragma unroll
    for (int mi = 0; mi < 4; mi++)
#pragma unroll
      for (int ni = 0; ni < 4; ni++) {
        accg[mi][ni] = __builtin_amdgcn_mfma_f32_16x16x32_bf16(af[mi], bg[ni], accg[mi][ni], 0, 0, 0);
        accu[mi][ni] = __builtin_amdgcn_mfma_f32_16x16x32_bf16(af[mi], bu[ni], accu[mi][ni], 0, 0, 0);
      }
  };

  stage(0, 0);
  stage(1, 1);
  const int NKS = HD / 32;
  for (int ks = 0; ks < NKS; ks++) {
    if (ks < NKS - 1) {
      S_WAITCNT_VMCNT(6);    // tile ks landed (own); <=2 younger stages fly
    } else {
      S_WAITCNT_VMCNT(0);
    }
    wave_barrier();          // all waves: tile ks ready AND compute(ks-1) done
    if (ks + 2 < NKS) stage((ks + 2) % 3, ks + 2);
    compute(ks % 3);
  }

  const int rh = lane >> 4;
#pragma unroll
  for (int mi = 0; mi < 4; mi++)
#pragma unroll
    for (int ni = 0; ni < 4; ni++)
#pragma unroll
      for (int j = 0; j < 4; j++) {
        int grow = rowbase + wr * 64 + mi * 16 + rh * 4 + j;
        if (grow < rowend) {
          int gcol = i0 + wc * 64 + ni * 16 + rl;
          float g = accg[mi][ni][j], u = accu[mi][ni][j];
          float val = g / (1.f + __expf(-g)) * u;
          act[(size_t)grow * NI + gcol] = f2bf(val);
        }
      }
}

// ---------------- grouped GEMM 2: y[row] = act[row] @ Wd  (no atomics) ------
// Same one-barrier depth-3 schedule.  LDS 3 x 16KB = 48KB, 3 blocks/CU.
__launch_bounds__(256, 3)
__global__ void gemm2_kernel(const unsigned short* __restrict__ act,
                             const unsigned short* __restrict__ Wdt,
                             unsigned short* __restrict__ y,
                             const int* __restrict__ cnt) {
  const int f = blockIdx.x + 16 * (blockIdx.y + 32 * blockIdx.z);
  const int e = f & 7;
  const int rem = f >> 3;          // 0..511
  const int nt = rem >> 5;         // 0..15
  const int mt = rem & 31;         // 0..31
  const int c = cnt[e];
  if (mt * 128 >= c) return;
  const int off = cnt[8 + e];
  const int rowbase = off + mt * 128, rowend = off + c;
  const int n0 = nt * 128;
  __shared__ __align__(16) char smem[49152];
  const int lane = threadIdx.x & 63, w = threadIdx.x >> 6;
  const int wr = w >> 1, wc = w & 1;

  const int rr0 = w * 16 + (lane >> 2);
  const int rr1 = rr0 + 64;
  const int q0 = (lane & 3) ^ ((rr0 >> 1) & 3);
  const int q1 = (lane & 3) ^ ((rr1 >> 1) & 3);
  int g0 = rowbase + rr0; if (g0 > rowend - 1) g0 = rowend - 1;
  int g1 = rowbase + rr1; if (g1 > rowend - 1) g1 = rowend - 1;
  const size_t aA0 = (size_t)g0 * NI;
  const size_t aA1 = (size_t)g1 * NI;
  const size_t bB0 = ((size_t)e * HD + n0 + rr0) * NI;
  const size_t bB1 = ((size_t)e * HD + n0 + rr1) * NI;
  const int ldsA = w * 1024;

  f32x4 zero = {0.f, 0.f, 0.f, 0.f};
  f32x4 acc[4][4];
#pragma unroll
  for (int a = 0; a < 4; a++)
#pragma unroll
    for (int b = 0; b < 4; b++) acc[a][b] = zero;

  auto stage = [&](int buf, int ks) {
    const int k0 = ks * 32;
    char* base = smem + buf * 16384;
    gload_lds16(act + aA0 + k0 + q0 * 8, base + ldsA);
    gload_lds16(act + aA1 + k0 + q1 * 8, base + ldsA + 4096);
    gload_lds16(Wdt + bB0 + k0 + q0 * 8, base + 8192 + ldsA);
    gload_lds16(Wdt + bB1 + k0 + q1 * 8, base + 8192 + ldsA + 4096);
  };
  const int rl = lane & 15, kslot = lane >> 4;
  auto compute = [&](int buf) {
    const char* base = smem + buf * 16384;
    bf16x8 af[4], bf[4];
#pragma unroll
    for (int mi = 0; mi < 4; mi++) {
      int r = wr * 64 + mi * 16 + rl;
      int byt = r * 64 + ((kslot ^ ((r >> 1) & 3)) << 4);
      af[mi] = *(const bf16x8*)(base + byt);
    }
#pragma unroll
    for (int ni = 0; ni < 4; ni++) {
      int r = wc * 64 + ni * 16 + rl;
      int byt = r * 64 + ((kslot ^ ((r >> 1) & 3)) << 4);
      bf[ni] = *(const bf16x8*)(base + 8192 + byt);
    }
#pragma unroll
    for (int mi = 0; mi < 4; mi++)
#pragma unroll
      for (int ni = 0; ni < 4; ni++)
        acc[mi][ni] = __builtin_amdgcn_mfma_f32_16x16x32_bf16(af[mi], bf[ni], acc[mi][ni], 0, 0, 0);
  };

  stage(0, 0);
  stage(1, 1);
  const int NKS = NI / 32;
  for (int ks = 0; ks < NKS; ks++) {
    if (ks < NKS - 1) {
      S_WAITCNT_VMCNT(4);
    } else {
      S_WAITCNT_VMCNT(0);
    }
    wave_barrier();
    if (ks + 2 < NKS) stage((ks + 2) % 3, ks + 2);
    compute(ks % 3);
  }

  const int rh = lane >> 4;
#pragma unroll
  for (int mi = 0; mi < 4; mi++)
#pragma unroll
    for (int ni = 0; ni < 4; ni++)
#pragma unroll
      for (int j = 0; j < 4; j++) {
        int grow = rowbase + wr * 64 + mi * 16 + rh * 4 + j;
        if (grow < rowend) {
          int gcol = n0 + wc * 64 + ni * 16 + rl;
          y[(size_t)grow * HD + gcol] = f2bf(acc[mi][ni][j]);
        }
      }
}

// ---------------- combine: out[t] = w0*y[r0] + w1*y[r1] ----------------
__global__ void combine_kernel(const unsigned short* __restrict__ y,
                               const int2* __restrict__ tok2row,
                               const int4* __restrict__ tokinfo,
                               float* __restrict__ out) {
  int t = blockIdx.x, tid = threadIdx.x;
  int2 rr = tok2row[t];
  int4 info = tokinfo[t];
  float w0 = __int_as_float(info.z), w1 = __int_as_float(info.w);
  ushort8 a = ((const ushort8*)(y + (size_t)rr.x * HD))[tid];
  ushort8 b = ((const ushort8*)(y + (size_t)rr.y * HD))[tid];
  float4 o0, o1;
  o0.x = w0 * bf2f(a[0]) + w1 * bf2f(b[0]);
  o0.y = w0 * bf2f(a[1]) + w1 * bf2f(b[1]);
  o0.z = w0 * bf2f(a[2]) + w1 * bf2f(b[2]);
  o0.w = w0 * bf2f(a[3]) + w1 * bf2f(b[3]);
  o1.x = w0 * bf2f(a[4]) + w1 * bf2f(b[4]);
  o1.y = w0 * bf2f(a[5]) + w1 * bf2f(b[5]);
  o1.z = w0 * bf2f(a[6]) + w1 * bf2f(b[6]);
  o1.w = w0 * bf2f(a[7]) + w1 * bf2f(b[7]);
  float4* op = (float4*)(out + (size_t)t * HD + tid * 8);
  op[0] = o0; op[1] = o1;
}

// ---------------- launch ----------------
extern "C" void kernel_launch(void* const* d_in, const int* in_sizes, int n_in,
                              void* d_out, int out_size, void* d_ws, size_t ws_size,
                              hipStream_t stream) {
  const float* x  = (const float*)d_in[0];
  const float* Wr = (const float*)d_in[1];
  const float* Wg = (const float*)d_in[2];
  const float* Wu = (const float*)d_in[3];
  const float* Wd = (const float*)d_in[4];
  float* out = (float*)d_out;
  char* ws = (char*)d_ws;

  // ws layout (bytes)
  unsigned short* xbf = (unsigned short*)(ws);                 // 16,777,216
  unsigned short* Wgt = (unsigned short*)(ws + 16777216);      // 46,137,344
  unsigned short* Wut = (unsigned short*)(ws + 62914560);      // 46,137,344
  unsigned short* Wdt = (unsigned short*)(ws + 109051904);     // 46,137,344
  unsigned short* act = (unsigned short*)(ws + 155189248);     // 23,068,672
  // y aliases Wgt: gemm1 (last reader of Wgt) completes before gemm2 writes y.
  unsigned short* yb  = (unsigned short*)(ws + 16777216);      // 33,554,432
  int4*  tokinfo      = (int4*)(ws + 178257920);               // 65,536
  int*   row_tok      = (int*)(ws + 178323456);                // 32,768
  int2*  tok2row      = (int2*)(ws + 178356224);               // 32,768
  int*   cnt          = (int*)(ws + 178388992);                // 128

  hipMemsetAsync(cnt, 0, 128, stream);

  // router (1024) + Wg/Wu transpose (5632) + Wd transpose (2816), one launch
  prepass_kernel<<<1024 + 5632 + 2816, 256, 0, stream>>>(
      x, Wr, Wg, Wu, Wd, out + (size_t)T_TOK * HD, xbf, Wgt, Wut, Wdt,
      tokinfo, cnt);
  route_finalize_kernel<<<1, 1024, 0, stream>>>(tokinfo, cnt, row_tok, tok2row);

  gemm1_kernel<<<dim3(11, 32, NE), 256, 0, stream>>>(xbf, Wgt, Wut, act, row_tok, cnt);
  gemm2_kernel<<<dim3(16, 32, NE), 256, 0, stream>>>(act, Wdt, yb, cnt);
  combine_kernel<<<T_TOK, 256, 0, stream>>>(yb, tok2row, tokinfo, out);
}